// Round 1
// baseline (1789.680 us; speedup 1.0000x reference)
//
#include <hip/hip_runtime.h>
#include <math.h>

// Problem constants (fixed by the reference):
// B=4, L=1024, D_IN=128, D_MODEL=512, N_LAYERS=2, N_CLASSES=3
// D_INNER=1024, D_STATE=64, D_CONV=2, DT_RANK=32, BL = 4096

__device__ __forceinline__ float silu_f(float v) {
  return v / (1.f + __expf(-v));
}

// C[4096, N] = A[4096, lda(:K)] * W[N, K]^T (+bias, +activation)
// 128x128 tile, 256 threads, 8x8 microtile, K-chunk 8, transposed LDS.
// ACT: 0 = none, 1 = softplus
template<int ACT>
__global__ void gemm_nt(const float* __restrict__ A, int lda,
                        const float* __restrict__ W,
                        const float* __restrict__ bias,
                        float* __restrict__ C, int ldc,
                        int N, int K)
{
  __shared__ float As[8][132];   // [k][m], stride 132 floats -> 528B rows (16B aligned)
  __shared__ float Ws[8][132];   // [k][n]
  const int tid  = threadIdx.x;
  const int m0   = blockIdx.y * 128;
  const int n0   = blockIdx.x * 128;
  const int lrow = tid >> 1;         // 0..127
  const int kh   = (tid & 1) * 4;    // 0 or 4
  const int tx   = tid & 15, ty = tid >> 4;

  const float* Aptr = A + (size_t)(m0 + lrow) * lda + kh;
  const int wrow = n0 + lrow;
  const float* Wptr = W + (size_t)wrow * K + kh;
  const bool wv = wrow < N;

  float4 ra = *(const float4*)Aptr;
  float4 rw = wv ? *(const float4*)Wptr : make_float4(0.f, 0.f, 0.f, 0.f);

  float acc[8][8];
  #pragma unroll
  for (int i = 0; i < 8; ++i)
    #pragma unroll
    for (int j = 0; j < 8; ++j) acc[i][j] = 0.f;

  for (int k0 = 0; k0 < K; k0 += 8) {
    __syncthreads();
    As[kh+0][lrow] = ra.x; As[kh+1][lrow] = ra.y;
    As[kh+2][lrow] = ra.z; As[kh+3][lrow] = ra.w;
    Ws[kh+0][lrow] = rw.x; Ws[kh+1][lrow] = rw.y;
    Ws[kh+2][lrow] = rw.z; Ws[kh+3][lrow] = rw.w;
    __syncthreads();
    if (k0 + 8 < K) {
      ra = *(const float4*)(Aptr + k0 + 8);
      if (wv) rw = *(const float4*)(Wptr + k0 + 8);
    }
    #pragma unroll
    for (int kk = 0; kk < 8; ++kk) {
      float a[8], w[8];
      *(float4*)&a[0] = *(const float4*)&As[kk][ty*8];
      *(float4*)&a[4] = *(const float4*)&As[kk][ty*8 + 4];
      *(float4*)&w[0] = *(const float4*)&Ws[kk][tx*8];
      *(float4*)&w[4] = *(const float4*)&Ws[kk][tx*8 + 4];
      #pragma unroll
      for (int i = 0; i < 8; ++i)
        #pragma unroll
        for (int j = 0; j < 8; ++j)
          acc[i][j] = fmaf(a[i], w[j], acc[i][j]);
    }
  }

  float bv[8];
  #pragma unroll
  for (int j = 0; j < 8; ++j) {
    int c = n0 + tx*8 + j;
    bv[j] = (bias != nullptr && c < N) ? bias[c] : 0.f;
  }
  #pragma unroll
  for (int i = 0; i < 8; ++i) {
    int gm = m0 + ty*8 + i;
    float* crow = C + (size_t)gm * ldc + n0 + tx*8;
    float o[8];
    #pragma unroll
    for (int j = 0; j < 8; ++j) {
      float v = acc[i][j] + bv[j];
      if (ACT == 1) v = (v > 20.f) ? v : log1pf(__expf(v));
      o[j] = v;
    }
    if (n0 + tx*8 + 7 < N) {
      *(float4*)crow       = make_float4(o[0], o[1], o[2], o[3]);
      *(float4*)(crow + 4) = make_float4(o[4], o[5], o[6], o[7]);
    } else {
      #pragma unroll
      for (int j = 0; j < 8; ++j)
        if (n0 + tx*8 + j < N) crow[j] = o[j];
    }
  }
}

// Depthwise causal conv (D_CONV=2) + silu.
// xz: [B*L][2048] (xc half = cols 0..1023), out xc: [B*L][1024]
__global__ void conv_silu_kernel(const float* __restrict__ xz,
                                 const float* __restrict__ cw,   // [1024][2]
                                 const float* __restrict__ cb,   // [1024]
                                 float* __restrict__ xc)
{
  int idx = blockIdx.x * 256 + threadIdx.x;     // over 4096*1024
  int d  = idx & 1023;
  int bl = idx >> 10;
  int t  = bl & 1023;
  float cur  = xz[((size_t)bl << 11) + d];
  float prev = t ? xz[((size_t)(bl - 1) << 11) + d] : 0.f;
  float v = fmaf(prev, cw[d*2], fmaf(cur, cw[d*2 + 1], cb[d]));
  xc[idx] = silu_f(v);
}

// Selective scan. One wave per (b,d), lane = s (D_STATE=64).
// dt/y may alias (in-place): dt[t] is read (and t+1 prefetched) before y[t] store.
__global__ __launch_bounds__(256)
void scan_kernel(const float* dt,                    // [B][L][1024]
                 const float* __restrict__ xc,       // [B][L][1024]
                 const float* __restrict__ dbc,      // [B][L][160]; B at +32, C at +96
                 const float* __restrict__ A_log,    // [1024][64]
                 const float* __restrict__ Dp,       // [1024]
                 float* y)                           // [B][L][1024]
{
  const int wid  = (blockIdx.x * blockDim.x + threadIdx.x) >> 6;  // 0..4095
  const int lane = threadIdx.x & 63;
  const int b = wid >> 10;
  const int d = wid & 1023;
  const float a   = -__expf(A_log[d*64 + lane]);
  const float dpv = Dp[d];
  const size_t td0 = ((size_t)b << 20) + d;
  const size_t bc0 = (size_t)b * 1024 * 160;

  float h = 0.f;
  float dtv = dt[td0];
  float xv  = xc[td0];
  float Bv  = dbc[bc0 + 32 + lane];
  float Cv  = dbc[bc0 + 96 + lane];

  for (int t = 0; t < 1024; ++t) {
    int tn = (t < 1023) ? t + 1 : t;          // clamped prefetch
    float dt_n = dt[td0 + ((size_t)tn << 10)];
    float x_n  = xc[td0 + ((size_t)tn << 10)];
    float B_n  = dbc[bc0 + (size_t)tn*160 + 32 + lane];
    float C_n  = dbc[bc0 + (size_t)tn*160 + 96 + lane];

    float dA = __expf(dtv * a);
    h = fmaf(h, dA, dtv * xv * Bv);
    float p = h * Cv;
    #pragma unroll
    for (int o = 32; o > 0; o >>= 1) p += __shfl_xor(p, o, 64);
    if (lane == 0) y[td0 + ((size_t)t << 10)] = fmaf(xv, dpv, p);

    dtv = dt_n; xv = x_n; Bv = B_n; Cv = C_n;
  }
}

// y *= silu(z), z = xz[:, 1024:2048]
__global__ void mul_silu_kernel(float* y, const float* __restrict__ xz)
{
  int idx = blockIdx.x * 256 + threadIdx.x;
  int d  = idx & 1023;
  int bl = idx >> 10;
  float z = xz[((size_t)bl << 11) + 1024 + d];
  y[idx] *= silu_f(z);
}

// out[b,c] = h[b, L-1, :] . fc_w[c, :] + fc_b[c]; grid 12 blocks x 64 threads
__global__ void head_kernel(const float* __restrict__ h,
                            const float* __restrict__ fc_w,
                            const float* __restrict__ fc_b,
                            float* __restrict__ out)
{
  int bc = blockIdx.x;            // 0..11
  int b = bc / 3, c = bc % 3;
  int lane = threadIdx.x;
  const float* hr = h + (size_t)(b*1024 + 1023) * 512;
  const float* wr = fc_w + c*512;
  float s = 0.f;
  #pragma unroll
  for (int i = 0; i < 8; ++i) s = fmaf(hr[lane + i*64], wr[lane + i*64], s);
  #pragma unroll
  for (int o = 32; o > 0; o >>= 1) s += __shfl_xor(s, o, 64);
  if (lane == 0) out[b*3 + c] = s + fc_b[c];
}

extern "C" void kernel_launch(void* const* d_in, const int* in_sizes, int n_in,
                              void* d_out, int out_size, void* d_ws, size_t ws_size,
                              hipStream_t stream)
{
  const float* x        = (const float*)d_in[0];
  const float* exp_w    = (const float*)d_in[1];
  const float* exp_b    = (const float*)d_in[2];
  const float* in_w     = (const float*)d_in[3];
  const float* conv_w   = (const float*)d_in[4];
  const float* conv_b   = (const float*)d_in[5];
  const float* xproj_w  = (const float*)d_in[6];
  const float* dtproj_w = (const float*)d_in[7];
  const float* dtproj_b = (const float*)d_in[8];
  const float* A_log    = (const float*)d_in[9];
  const float* Dp       = (const float*)d_in[10];
  const float* out_w    = (const float*)d_in[11];
  const float* fc_w     = (const float*)d_in[12];
  const float* fc_b     = (const float*)d_in[13];
  float* out = (float*)d_out;

  // Workspace layout (floats): 74.8 MB total, fully rewritten every call.
  float* ws      = (float*)d_ws;
  float* buf_h   = ws;                          // 4096*512
  float* buf_xz  = buf_h   + 4096*512;          // 4096*2048
  float* buf_xc  = buf_xz  + (size_t)4096*2048; // 4096*1024
  float* buf_dbc = buf_xc  + (size_t)4096*1024; // 4096*160
  float* buf_dt  = buf_dbc + (size_t)4096*160;  // 4096*1024 (also y, in place)

  dim3 blk(256);

  // expand: h = x @ exp_w^T + exp_b   [4096,512] K=128
  gemm_nt<0><<<dim3(4, 32), blk, 0, stream>>>(x, 128, exp_w, exp_b, buf_h, 512, 512, 128);

  for (int l = 0; l < 2; ++l) {
    // in_proj: xz = h @ in_w^T   [4096,2048] K=512
    gemm_nt<0><<<dim3(16, 32), blk, 0, stream>>>(buf_h, 512, in_w + (size_t)l*2048*512,
                                                 nullptr, buf_xz, 2048, 2048, 512);
    // conv(k=2) + silu -> xc
    conv_silu_kernel<<<16384, blk, 0, stream>>>(buf_xz, conv_w + l*2048, conv_b + l*1024, buf_xc);
    // xproj: dbc = xc @ xproj_w^T   [4096,160] K=1024
    gemm_nt<0><<<dim3(2, 32), blk, 0, stream>>>(buf_xc, 1024, xproj_w + (size_t)l*160*1024,
                                                nullptr, buf_dbc, 160, 160, 1024);
    // dtproj + bias + softplus: dt   [4096,1024] K=32
    gemm_nt<1><<<dim3(8, 32), blk, 0, stream>>>(buf_dbc, 160, dtproj_w + (size_t)l*1024*32,
                                                dtproj_b + l*1024, buf_dt, 1024, 1024, 32);
    // selective scan (+ x*Dp), y written in place over dt
    scan_kernel<<<1024, blk, 0, stream>>>(buf_dt, buf_xc, buf_dbc,
                                          A_log + (size_t)l*1024*64, Dp + l*1024, buf_dt);
    // y *= silu(z)
    mul_silu_kernel<<<16384, blk, 0, stream>>>(buf_dt, buf_xz);
    // out_proj: h = y @ out_w^T   [4096,512] K=1024
    gemm_nt<0><<<dim3(4, 32), blk, 0, stream>>>(buf_dt, 1024, out_w + (size_t)l*512*1024,
                                                nullptr, buf_h, 512, 512, 1024);
  }

  head_kernel<<<12, 64, 0, stream>>>(buf_h, fc_w, fc_b, out);
}

// Round 2
// 1451.874 us; speedup vs baseline: 1.2327x; 1.2327x over previous
//
#include <hip/hip_runtime.h>
#include <math.h>

// Problem constants (fixed by the reference):
// B=4, L=1024, D_IN=128, D_MODEL=512, N_LAYERS=2, N_CLASSES=3
// D_INNER=1024, D_STATE=64, D_CONV=2, DT_RANK=32, BL = 4096

__device__ __forceinline__ float silu_f(float v) {
  return v / (1.f + __expf(-v));
}

// C[4096, N] = A[4096, lda(:K)] * W[N, K]^T (+bias, +activation)
// 128x128 tile, 256 threads, 8x8 microtile, K-chunk 8, transposed LDS.
// ACT: 0 = none, 1 = softplus
template<int ACT>
__global__ void gemm_nt(const float* __restrict__ A, int lda,
                        const float* __restrict__ W,
                        const float* __restrict__ bias,
                        float* __restrict__ C, int ldc,
                        int N, int K)
{
  __shared__ float As[8][132];   // [k][m], stride 132 floats -> 528B rows (16B aligned)
  __shared__ float Ws[8][132];   // [k][n]
  const int tid  = threadIdx.x;
  const int m0   = blockIdx.y * 128;
  const int n0   = blockIdx.x * 128;
  const int lrow = tid >> 1;         // 0..127
  const int kh   = (tid & 1) * 4;    // 0 or 4
  const int tx   = tid & 15, ty = tid >> 4;

  const float* Aptr = A + (size_t)(m0 + lrow) * lda + kh;
  const int wrow = n0 + lrow;
  const float* Wptr = W + (size_t)wrow * K + kh;
  const bool wv = wrow < N;

  float4 ra = *(const float4*)Aptr;
  float4 rw = wv ? *(const float4*)Wptr : make_float4(0.f, 0.f, 0.f, 0.f);

  float acc[8][8];
  #pragma unroll
  for (int i = 0; i < 8; ++i)
    #pragma unroll
    for (int j = 0; j < 8; ++j) acc[i][j] = 0.f;

  for (int k0 = 0; k0 < K; k0 += 8) {
    __syncthreads();
    As[kh+0][lrow] = ra.x; As[kh+1][lrow] = ra.y;
    As[kh+2][lrow] = ra.z; As[kh+3][lrow] = ra.w;
    Ws[kh+0][lrow] = rw.x; Ws[kh+1][lrow] = rw.y;
    Ws[kh+2][lrow] = rw.z; Ws[kh+3][lrow] = rw.w;
    __syncthreads();
    if (k0 + 8 < K) {
      ra = *(const float4*)(Aptr + k0 + 8);
      if (wv) rw = *(const float4*)(Wptr + k0 + 8);
    }
    #pragma unroll
    for (int kk = 0; kk < 8; ++kk) {
      float a[8], w[8];
      *(float4*)&a[0] = *(const float4*)&As[kk][ty*8];
      *(float4*)&a[4] = *(const float4*)&As[kk][ty*8 + 4];
      *(float4*)&w[0] = *(const float4*)&Ws[kk][tx*8];
      *(float4*)&w[4] = *(const float4*)&Ws[kk][tx*8 + 4];
      #pragma unroll
      for (int i = 0; i < 8; ++i)
        #pragma unroll
        for (int j = 0; j < 8; ++j)
          acc[i][j] = fmaf(a[i], w[j], acc[i][j]);
    }
  }

  float bv[8];
  #pragma unroll
  for (int j = 0; j < 8; ++j) {
    int c = n0 + tx*8 + j;
    bv[j] = (bias != nullptr && c < N) ? bias[c] : 0.f;
  }
  #pragma unroll
  for (int i = 0; i < 8; ++i) {
    int gm = m0 + ty*8 + i;
    float* crow = C + (size_t)gm * ldc + n0 + tx*8;
    float o[8];
    #pragma unroll
    for (int j = 0; j < 8; ++j) {
      float v = acc[i][j] + bv[j];
      if (ACT == 1) v = (v > 20.f) ? v : log1pf(__expf(v));
      o[j] = v;
    }
    if (n0 + tx*8 + 7 < N) {
      *(float4*)crow       = make_float4(o[0], o[1], o[2], o[3]);
      *(float4*)(crow + 4) = make_float4(o[4], o[5], o[6], o[7]);
    } else {
      #pragma unroll
      for (int j = 0; j < 8; ++j)
        if (n0 + tx*8 + j < N) crow[j] = o[j];
    }
  }
}

// Depthwise causal conv (D_CONV=2) + silu.
// xz: [B*L][2048] (xc half = cols 0..1023), out xc: [B*L][1024]
__global__ void conv_silu_kernel(const float* __restrict__ xz,
                                 const float* __restrict__ cw,   // [1024][2]
                                 const float* __restrict__ cb,   // [1024]
                                 float* __restrict__ xc)
{
  int idx = blockIdx.x * 256 + threadIdx.x;     // over 4096*1024
  int d  = idx & 1023;
  int bl = idx >> 10;
  int t  = bl & 1023;
  float cur  = xz[((size_t)bl << 11) + d];
  float prev = t ? xz[((size_t)(bl - 1) << 11) + d] : 0.f;
  float v = fmaf(prev, cw[d*2], fmaf(cur, cw[d*2 + 1], cb[d]));
  xc[idx] = silu_f(v);
}

// Selective scan. One wave per (b,d) chain, lane = s (D_STATE=64).
// Batched reduction: accumulate p = h*C for 16 timesteps into a wave-private
// LDS tile P[16][64] (1 ds_write/t), then transpose-read (4 ds_read_b128/lane),
// in-register sum of 16, 2 shuffle stages, one exec-masked store of 16 y's.
// This replaces the 6-stage/t butterfly: DS ops per 16 t drop 96 -> 22.
// x*Dp is folded in by lane tt at write time (no extra DS op).
// y is written into the xz buffer (cols 0..1023, row stride 2048), so dt/xc
// stay read-only -> uniform dt/xc loads can scalarize to s_load.
__global__ __launch_bounds__(256, 4)
void scan_kernel(const float* __restrict__ dt,    // [B][L][1024]
                 const float* __restrict__ xc,    // [B][L][1024]
                 const float* __restrict__ dbc,   // [B][L][160]; B at +32, C at +96
                 const float* __restrict__ A_log, // [1024][64]
                 const float* __restrict__ Dp,    // [1024]
                 float* __restrict__ y)           // [B][L][2048], cols 0..1023
{
  __shared__ float P[4][16][68];   // per-wave [t][s] tile; pad 68 keeps b128 16B-aligned
  const int lane = threadIdx.x & 63;
  const int wrp  = threadIdx.x >> 6;
  const int wid  = __builtin_amdgcn_readfirstlane(blockIdx.x * 4 + wrp); // 0..4095
  const int b = wid >> 10;
  const int d = wid & 1023;
  float (*Pw)[68] = P[wrp];

  const float a   = -__expf(A_log[d*64 + lane]);
  const float dpv = Dp[d];
  const float* dtp = dt  + ((size_t)b << 20) + d;       // + t*1024
  const float* xcp = xc  + ((size_t)b << 20) + d;
  const float* bcp = dbc + (size_t)b * 163840 + lane;   // + t*160 (+32 / +96)
  float*       yp  = y   + ((size_t)b << 21) + d;       // + t*2048

  const int tt_r = lane >> 2;          // which timestep this lane reduces
  const int c0   = (lane & 3) << 4;    // which 16-state chunk

  float h = 0.f;
  for (int t0 = 0; t0 < 1024; t0 += 16) {
    // --- batch-load phase: 16 independent loads per stream, overlap latency ---
    float Bv[16], Cv[16], dtv[16], xv[16];
    #pragma unroll
    for (int tt = 0; tt < 16; ++tt) {
      size_t off = (size_t)(t0 + tt);
      dtv[tt] = dtp[off << 10];          // wave-uniform address
      xv[tt]  = xcp[off << 10];          // wave-uniform address
      Bv[tt]  = bcp[off * 160 + 32];     // coalesced 64 lanes
      Cv[tt]  = bcp[off * 160 + 96];
    }
    // --- recurrence phase (serial in t, chain = mul->exp->fma) ---
    #pragma unroll
    for (int tt = 0; tt < 16; ++tt) {
      float dA = __expf(dtv[tt] * a);
      h = fmaf(h, dA, dtv[tt] * xv[tt] * Bv[tt]);
      float p = h * Cv[tt];
      if (lane == tt) p = fmaf(xv[tt], dpv, p);   // fold x*Dp into row tt's sum
      Pw[tt][lane] = p;
    }
    // --- batched reduction: lane L sums 16 states of timestep L>>2 ---
    float4 s0 = *(const float4*)&Pw[tt_r][c0];
    float4 s1 = *(const float4*)&Pw[tt_r][c0 + 4];
    float4 s2 = *(const float4*)&Pw[tt_r][c0 + 8];
    float4 s3 = *(const float4*)&Pw[tt_r][c0 + 12];
    float r = ((s0.x + s0.y) + (s0.z + s0.w))
            + ((s1.x + s1.y) + (s1.z + s1.w))
            + ((s2.x + s2.y) + (s2.z + s2.w))
            + ((s3.x + s3.y) + (s3.z + s3.w));
    r += __shfl_xor(r, 1, 64);
    r += __shfl_xor(r, 2, 64);
    if ((lane & 3) == 0)
      yp[(size_t)(t0 + tt_r) << 11] = r;
  }
}

// y *= silu(z); y lives in xz cols 0..1023, z in cols 1024..2047
__global__ void mul_silu_kernel(float* __restrict__ xz)
{
  int idx = blockIdx.x * 256 + threadIdx.x;   // over 4096*1024
  int d  = idx & 1023;
  int bl = idx >> 10;
  float* row = xz + ((size_t)bl << 11);
  row[d] *= silu_f(row[1024 + d]);
}

// out[b,c] = h[b, L-1, :] . fc_w[c, :] + fc_b[c]; grid 12 blocks x 64 threads
__global__ void head_kernel(const float* __restrict__ h,
                            const float* __restrict__ fc_w,
                            const float* __restrict__ fc_b,
                            float* __restrict__ out)
{
  int bc = blockIdx.x;            // 0..11
  int b = bc / 3, c = bc % 3;
  int lane = threadIdx.x;
  const float* hr = h + (size_t)(b*1024 + 1023) * 512;
  const float* wr = fc_w + c*512;
  float s = 0.f;
  #pragma unroll
  for (int i = 0; i < 8; ++i) s = fmaf(hr[lane + i*64], wr[lane + i*64], s);
  #pragma unroll
  for (int o = 32; o > 0; o >>= 1) s += __shfl_xor(s, o, 64);
  if (lane == 0) out[b*3 + c] = s + fc_b[c];
}

extern "C" void kernel_launch(void* const* d_in, const int* in_sizes, int n_in,
                              void* d_out, int out_size, void* d_ws, size_t ws_size,
                              hipStream_t stream)
{
  const float* x        = (const float*)d_in[0];
  const float* exp_w    = (const float*)d_in[1];
  const float* exp_b    = (const float*)d_in[2];
  const float* in_w     = (const float*)d_in[3];
  const float* conv_w   = (const float*)d_in[4];
  const float* conv_b   = (const float*)d_in[5];
  const float* xproj_w  = (const float*)d_in[6];
  const float* dtproj_w = (const float*)d_in[7];
  const float* dtproj_b = (const float*)d_in[8];
  const float* A_log    = (const float*)d_in[9];
  const float* Dp       = (const float*)d_in[10];
  const float* out_w    = (const float*)d_in[11];
  const float* fc_w     = (const float*)d_in[12];
  const float* fc_b     = (const float*)d_in[13];
  float* out = (float*)d_out;

  // Workspace layout (floats): 74.8 MB total, fully rewritten every call.
  float* ws      = (float*)d_ws;
  float* buf_h   = ws;                          // 4096*512
  float* buf_xz  = buf_h   + 4096*512;          // 4096*2048  (y reuses cols 0..1023)
  float* buf_xc  = buf_xz  + (size_t)4096*2048; // 4096*1024
  float* buf_dbc = buf_xc  + (size_t)4096*1024; // 4096*160
  float* buf_dt  = buf_dbc + (size_t)4096*160;  // 4096*1024

  dim3 blk(256);

  // expand: h = x @ exp_w^T + exp_b   [4096,512] K=128
  gemm_nt<0><<<dim3(4, 32), blk, 0, stream>>>(x, 128, exp_w, exp_b, buf_h, 512, 512, 128);

  for (int l = 0; l < 2; ++l) {
    // in_proj: xz = h @ in_w^T   [4096,2048] K=512
    gemm_nt<0><<<dim3(16, 32), blk, 0, stream>>>(buf_h, 512, in_w + (size_t)l*2048*512,
                                                 nullptr, buf_xz, 2048, 2048, 512);
    // conv(k=2) + silu -> xc
    conv_silu_kernel<<<16384, blk, 0, stream>>>(buf_xz, conv_w + l*2048, conv_b + l*1024, buf_xc);
    // xproj: dbc = xc @ xproj_w^T   [4096,160] K=1024
    gemm_nt<0><<<dim3(2, 32), blk, 0, stream>>>(buf_xc, 1024, xproj_w + (size_t)l*160*1024,
                                                nullptr, buf_dbc, 160, 160, 1024);
    // dtproj + bias + softplus: dt   [4096,1024] K=32
    gemm_nt<1><<<dim3(8, 32), blk, 0, stream>>>(buf_dbc, 160, dtproj_w + (size_t)l*1024*32,
                                                dtproj_b + l*1024, buf_dt, 1024, 1024, 32);
    // selective scan (+ x*Dp); y written into xz cols 0..1023 (stride 2048)
    scan_kernel<<<1024, blk, 0, stream>>>(buf_dt, buf_xc, buf_dbc,
                                          A_log + (size_t)l*1024*64, Dp + l*1024, buf_xz);
    // y *= silu(z), in place inside xz
    mul_silu_kernel<<<16384, blk, 0, stream>>>(buf_xz);
    // out_proj: h = y @ out_w^T   [4096,512] K=1024, A stride 2048
    gemm_nt<0><<<dim3(4, 32), blk, 0, stream>>>(buf_xz, 2048, out_w + (size_t)l*512*1024,
                                                nullptr, buf_h, 512, 512, 1024);
  }

  head_kernel<<<12, 64, 0, stream>>>(buf_h, fc_w, fc_b, out);
}

// Round 3
// 1139.717 us; speedup vs baseline: 1.5703x; 1.2739x over previous
//
#include <hip/hip_runtime.h>
#include <math.h>

// Problem constants (fixed by the reference):
// B=4, L=1024, D_IN=128, D_MODEL=512, N_LAYERS=2, N_CLASSES=3
// D_INNER=1024, D_STATE=64, D_CONV=2, DT_RANK=32, BL = 4096

__device__ __forceinline__ float silu_f(float v) {
  return v / (1.f + __expf(-v));
}

// C = A*W^T (+bias, +act). M fixed = 4096-ish multiple of 128 (full tiles).
// TA=0: A is [M][K] row-major (lda=K-stride). TA=1: A is [K][M] row-major (lda=M-stride).
// TC=0: C is [M][N] (ldc=N-stride).      TC=1: C is [N][M] (ldc=M-stride).
// ACT: 0 none, 1 softplus, 2 silu.
// 128x128 tile, 256 threads, 8x8 microtile, K-chunk 8, transposed LDS As[k][m].
template<int TA, int TC, int ACT>
__global__ void gemm_k(const float* __restrict__ A, int lda,
                       const float* __restrict__ W,      // [N][K]
                       const float* __restrict__ bias,   // per n, or null
                       float* __restrict__ C, int ldc,
                       int N, int K)
{
  __shared__ float As[8][132];   // [k][m] pad->528B rows (16B aligned)
  __shared__ float Ws[8][132];   // [k][n]
  const int tid  = threadIdx.x;
  const int m0   = blockIdx.y * 128;
  const int n0   = blockIdx.x * 128;
  const int lrow = tid >> 1;         // 0..127
  const int kh   = (tid & 1) * 4;    // 0 or 4
  const int tx   = tid & 15, ty = tid >> 4;

  const int wrow = n0 + lrow;
  const float* Wptr = W + (size_t)wrow * K + kh;
  const bool wv = wrow < N;

  const int at_k = tid >> 5;          // 0..7   (TA=1)
  const int at_m = (tid & 31) * 4;    // 0..124 (TA=1)
  const float* Aptr = (TA == 0) ? (A + (size_t)(m0 + lrow) * lda + kh)
                                : (A + (size_t)at_k * lda + m0 + at_m);

  float4 ra = *(const float4*)Aptr;
  float4 rw = wv ? *(const float4*)Wptr : make_float4(0.f, 0.f, 0.f, 0.f);

  float acc[8][8];
  #pragma unroll
  for (int i = 0; i < 8; ++i)
    #pragma unroll
    for (int j = 0; j < 8; ++j) acc[i][j] = 0.f;

  for (int k0 = 0; k0 < K; k0 += 8) {
    __syncthreads();
    if (TA == 0) {
      As[kh+0][lrow] = ra.x; As[kh+1][lrow] = ra.y;
      As[kh+2][lrow] = ra.z; As[kh+3][lrow] = ra.w;
    } else {
      *(float4*)&As[at_k][at_m] = ra;
    }
    Ws[kh+0][lrow] = rw.x; Ws[kh+1][lrow] = rw.y;
    Ws[kh+2][lrow] = rw.z; Ws[kh+3][lrow] = rw.w;
    __syncthreads();
    if (k0 + 8 < K) {
      if (TA == 0) ra = *(const float4*)(Aptr + k0 + 8);
      else { Aptr += (size_t)8 * lda; ra = *(const float4*)Aptr; }
      if (wv) rw = *(const float4*)(Wptr + k0 + 8);
    }
    #pragma unroll
    for (int kk = 0; kk < 8; ++kk) {
      float a[8], w[8];
      *(float4*)&a[0] = *(const float4*)&As[kk][ty*8];
      *(float4*)&a[4] = *(const float4*)&As[kk][ty*8 + 4];
      *(float4*)&w[0] = *(const float4*)&Ws[kk][tx*8];
      *(float4*)&w[4] = *(const float4*)&Ws[kk][tx*8 + 4];
      #pragma unroll
      for (int i = 0; i < 8; ++i)
        #pragma unroll
        for (int j = 0; j < 8; ++j)
          acc[i][j] = fmaf(a[i], w[j], acc[i][j]);
    }
  }

  float bv[8];
  #pragma unroll
  for (int j = 0; j < 8; ++j) {
    int nn = n0 + tx*8 + j;
    bv[j] = (bias != nullptr && nn < N) ? bias[nn] : 0.f;
  }

  if (TC == 0) {
    #pragma unroll
    for (int i = 0; i < 8; ++i) {
      int gm = m0 + ty*8 + i;
      float* crow = C + (size_t)gm * ldc + n0 + tx*8;
      float o[8];
      #pragma unroll
      for (int j = 0; j < 8; ++j) {
        float v = acc[i][j] + bv[j];
        if (ACT == 1) v = (v > 20.f) ? v : log1pf(__expf(v));
        if (ACT == 2) v = silu_f(v);
        o[j] = v;
      }
      if (n0 + tx*8 + 7 < N) {
        *(float4*)crow       = make_float4(o[0], o[1], o[2], o[3]);
        *(float4*)(crow + 4) = make_float4(o[4], o[5], o[6], o[7]);
      } else {
        #pragma unroll
        for (int j = 0; j < 8; ++j)
          if (n0 + tx*8 + j < N) crow[j] = o[j];
      }
    }
  } else {
    #pragma unroll
    for (int j = 0; j < 8; ++j) {
      int nn = n0 + tx*8 + j;
      if (nn < N) {
        float* crow = C + (size_t)nn * ldc + m0 + ty*8;
        float o[8];
        #pragma unroll
        for (int i = 0; i < 8; ++i) {
          float v = acc[i][j] + bv[j];
          if (ACT == 1) v = (v > 20.f) ? v : log1pf(__expf(v));
          if (ACT == 2) v = silu_f(v);
          o[i] = v;
        }
        *(float4*)crow       = make_float4(o[0], o[1], o[2], o[3]);
        *(float4*)(crow + 4) = make_float4(o[4], o[5], o[6], o[7]);
      }
    }
  }
}

// Depthwise causal conv (D_CONV=2) + silu, with 64x64 LDS transpose.
// in:  xcp [B*1024 t][1024 d] (pre-conv half of in_proj)
// out: xcT [1024 d][4096 bl]  (time-major, bl = b*1024 + t)
__global__ void conv_t_kernel(const float* __restrict__ xcp,
                              const float* __restrict__ cw,   // [1024][2]
                              const float* __restrict__ cb,   // [1024]
                              float* __restrict__ xcT)
{
  __shared__ float tile[64][65];
  const int blk = blockIdx.x;            // b*256 + tt*16 + dd
  const int b  = blk >> 8;
  const int tt = (blk >> 4) & 15;
  const int dd = blk & 15;
  const int t0 = tt * 64, d0 = dd * 64;
  const int tid = threadIdx.x;

  #pragma unroll
  for (int i = 0; i < 16; ++i) {
    int idx = i * 256 + tid;
    int t = idx >> 6, d = idx & 63;
    int gt = t0 + t;
    size_t rcur = ((size_t)(b * 1024 + gt) << 10) + d0 + d;
    float cur  = xcp[rcur];
    float prev = (gt > 0) ? xcp[rcur - 1024] : 0.f;
    float v = fmaf(prev, cw[(d0+d)*2], fmaf(cur, cw[(d0+d)*2 + 1], cb[d0+d]));
    tile[t][d] = silu_f(v);
  }
  __syncthreads();
  #pragma unroll
  for (int i = 0; i < 16; ++i) {
    int idx = i * 256 + tid;
    int d = idx >> 6, t = idx & 63;
    xcT[((size_t)(d0 + d) << 12) + b * 1024 + t0 + t] = tile[t][d];
  }
}

// Selective scan, time-major operands. One wave per (b,d), lane = s.
// Reads dtT/xcT/zsT rows (contiguous 64B per chunk per stream), dbc coalesced.
// y = (scan + x*Dp) * silu(z) written IN PLACE over xcT (dead after xproj).
__global__ __launch_bounds__(256, 4)
void scan_kernel(const float* __restrict__ dtT,   // [1024][4096]
                 float* __restrict__ xcT,         // [1024][4096]; y in place
                 const float* __restrict__ zsT,   // [1024][4096], silu(z)
                 const float* __restrict__ dbc,   // [B][1024][160]; B at +32, C at +96
                 const float* __restrict__ A_log, // [1024][64]
                 const float* __restrict__ Dp)    // [1024]
{
  __shared__ float P[4][16][68];   // per-wave [t][s]; pad 68 keeps b128 16B-aligned
  const int lane = threadIdx.x & 63;
  const int wrp  = threadIdx.x >> 6;
  const int wid  = __builtin_amdgcn_readfirstlane(blockIdx.x * 4 + wrp); // 0..4095
  const int b = wid >> 10;
  const int d = wid & 1023;
  float (*Pw)[68] = P[wrp];

  const float a   = -__expf(A_log[d*64 + lane]);
  const float dpv = Dp[d];
  const size_t row = ((size_t)d << 12) + b * 1024;
  const float* dtp = dtT + row;
  float*       xyp = xcT + row;
  const float* zsp = zsT + row;
  const float* bcp = dbc + (size_t)b * 163840 + lane;   // + t*160 (+32 / +96)

  const int tt_r = lane >> 2;          // which timestep this lane reduces
  const int c0   = (lane & 3) << 4;    // which 16-state chunk

  float h = 0.f;
  for (int t0 = 0; t0 < 1024; t0 += 16) {
    float4 dq[4], xq[4];
    #pragma unroll
    for (int i = 0; i < 4; ++i) {
      dq[i] = *(const float4*)(dtp + t0 + i*4);
      xq[i] = *(const float4*)(xyp + t0 + i*4);
    }
    const float* dtv = reinterpret_cast<const float*>(dq);
    const float* xv  = reinterpret_cast<const float*>(xq);
    float zs = zsp[t0 + tt_r];                       // per-lane, 64B/wave
    float Bv[16], Cv[16];
    #pragma unroll
    for (int tt = 0; tt < 16; ++tt) {
      Bv[tt] = bcp[(size_t)(t0 + tt) * 160 + 32];
      Cv[tt] = bcp[(size_t)(t0 + tt) * 160 + 96];
    }
    // serial recurrence
    #pragma unroll
    for (int tt = 0; tt < 16; ++tt) {
      float dA = __expf(dtv[tt] * a);
      h = fmaf(h, dA, dtv[tt] * xv[tt] * Bv[tt]);
      float p = h * Cv[tt];
      if (lane == tt) p = fmaf(xv[tt], dpv, p);      // fold x*Dp into row tt
      Pw[tt][lane] = p;
    }
    // batched reduction: lane L sums 16 states of timestep L>>2
    float4 s0 = *(const float4*)&Pw[tt_r][c0];
    float4 s1 = *(const float4*)&Pw[tt_r][c0 + 4];
    float4 s2 = *(const float4*)&Pw[tt_r][c0 + 8];
    float4 s3 = *(const float4*)&Pw[tt_r][c0 + 12];
    float r = ((s0.x + s0.y) + (s0.z + s0.w))
            + ((s1.x + s1.y) + (s1.z + s1.w))
            + ((s2.x + s2.y) + (s2.z + s2.w))
            + ((s3.x + s3.y) + (s3.z + s3.w));
    r += __shfl_xor(r, 1, 64);
    r += __shfl_xor(r, 2, 64);
    if ((lane & 3) == 0)
      xyp[t0 + tt_r] = r * zs;                       // y over xc, contiguous 16 dwords
  }
}

// out[b,c] = h[b, L-1, :] . fc_w[c, :] + fc_b[c]; grid 12 blocks x 64 threads
__global__ void head_kernel(const float* __restrict__ h,
                            const float* __restrict__ fc_w,
                            const float* __restrict__ fc_b,
                            float* __restrict__ out)
{
  int bc = blockIdx.x;            // 0..11
  int b = bc / 3, c = bc % 3;
  int lane = threadIdx.x;
  const float* hr = h + (size_t)(b*1024 + 1023) * 512;
  const float* wr = fc_w + c*512;
  float s = 0.f;
  #pragma unroll
  for (int i = 0; i < 8; ++i) s = fmaf(hr[lane + i*64], wr[lane + i*64], s);
  #pragma unroll
  for (int o = 32; o > 0; o >>= 1) s += __shfl_xor(s, o, 64);
  if (lane == 0) out[b*3 + c] = s + fc_b[c];
}

extern "C" void kernel_launch(void* const* d_in, const int* in_sizes, int n_in,
                              void* d_out, int out_size, void* d_ws, size_t ws_size,
                              hipStream_t stream)
{
  const float* x        = (const float*)d_in[0];
  const float* exp_w    = (const float*)d_in[1];
  const float* exp_b    = (const float*)d_in[2];
  const float* in_w     = (const float*)d_in[3];
  const float* conv_w   = (const float*)d_in[4];
  const float* conv_b   = (const float*)d_in[5];
  const float* xproj_w  = (const float*)d_in[6];
  const float* dtproj_w = (const float*)d_in[7];
  const float* dtproj_b = (const float*)d_in[8];
  const float* A_log    = (const float*)d_in[9];
  const float* Dp       = (const float*)d_in[10];
  const float* out_w    = (const float*)d_in[11];
  const float* fc_w     = (const float*)d_in[12];
  const float* fc_b     = (const float*)d_in[13];
  float* out = (float*)d_out;

  // Workspace (floats), 74.5 MB total, fully rewritten every call:
  float* ws        = (float*)d_ws;
  float* buf_h     = ws;                               // 4096*512
  float* buf_xcpre = buf_h     + (size_t)4096*512;     // 4096*1024 (pre-conv xc)
  float* buf_xcT   = buf_xcpre + (size_t)4096*1024;    // [1024][4096]; y in place
  float* buf_zsT   = buf_xcT   + (size_t)4096*1024;    // [1024][4096] silu(z)
  float* buf_dbc   = buf_zsT   + (size_t)4096*1024;    // 4096*160
  float* buf_dtT   = buf_dbc   + (size_t)4096*160;     // [1024][4096]

  dim3 blk(256);

  // expand: h = x @ exp_w^T + exp_b   [4096,512] K=128
  gemm_k<0,0,0><<<dim3(4, 32), blk, 0, stream>>>(x, 128, exp_w, exp_b, buf_h, 512, 512, 128);

  for (int l = 0; l < 2; ++l) {
    const float* inw = in_w + (size_t)l * 2048 * 512;
    // in_proj (xc half): xc_pre = h @ in_w[0:1024]^T   [4096,1024]
    gemm_k<0,0,0><<<dim3(8, 32), blk, 0, stream>>>(buf_h, 512, inw, nullptr,
                                                   buf_xcpre, 1024, 1024, 512);
    // in_proj (z half), transposed + silu: zsT = silu(h @ in_w[1024:2048]^T)^T  [1024][4096]
    gemm_k<0,1,2><<<dim3(8, 32), blk, 0, stream>>>(buf_h, 512, inw + (size_t)1024*512, nullptr,
                                                   buf_zsT, 4096, 1024, 512);
    // conv(k=2) + silu + transpose -> xcT [1024][4096]
    conv_t_kernel<<<1024, blk, 0, stream>>>(buf_xcpre, conv_w + l*2048, conv_b + l*1024, buf_xcT);
    // xproj (TN): dbc = xcT^T @ xproj_w^T   [4096,160] K=1024
    gemm_k<1,0,0><<<dim3(2, 32), blk, 0, stream>>>(buf_xcT, 4096, xproj_w + (size_t)l*160*1024,
                                                   nullptr, buf_dbc, 160, 160, 1024);
    // dtproj, transposed + softplus: dtT = softplus(dbc @ dtproj_w^T + b)^T  [1024][4096]
    gemm_k<0,1,1><<<dim3(8, 32), blk, 0, stream>>>(buf_dbc, 160, dtproj_w + (size_t)l*1024*32,
                                                   dtproj_b + l*1024, buf_dtT, 4096, 1024, 32);
    // selective scan; y = (scan + x*Dp)*silu(z) written over xcT
    scan_kernel<<<1024, blk, 0, stream>>>(buf_dtT, buf_xcT, buf_zsT, buf_dbc,
                                          A_log + (size_t)l*65536, Dp + l*1024);
    // out_proj (TN): h = yT^T @ out_w^T   [4096,512] K=1024
    gemm_k<1,0,0><<<dim3(4, 32), blk, 0, stream>>>(buf_xcT, 4096, out_w + (size_t)l*512*1024,
                                                   nullptr, buf_h, 512, 512, 1024);
  }

  head_kernel<<<12, 64, 0, stream>>>(buf_h, fc_w, fc_b, out);
}

// Round 7
// 577.877 us; speedup vs baseline: 3.0970x; 1.9722x over previous
//
#include <hip/hip_runtime.h>
#include <math.h>

// Problem constants: B=4, L=1024, D_IN=128, D_MODEL=512, N_LAYERS=2,
// N_CLASSES=3, D_INNER=1024, D_STATE=64, D_CONV=2, DT_RANK=32, BL=4096.
//
// Precision plan (values shrink ~1000x per layer; final output ~3e-8):
//  - residual h kept fp32 end-to-end (layer-2 h ~3e-8 is f16-subnormal).
//  - y (out_proj A operand) scaled by 2^14 before f16 conversion; out_proj
//    epilogue multiplies by 2^-14 (exact powers of two).

using half8  = __attribute__((ext_vector_type(8))) _Float16;
using half4v = __attribute__((ext_vector_type(4))) _Float16;
using f32x4  = __attribute__((ext_vector_type(4))) float;

#define Y_SCALE 16384.0f   // 2^14

__device__ __forceinline__ float silu_f(float v) {
  return v / (1.f + __expf(-v));
}

__device__ __forceinline__ half8 pack_f16(float4 a, float4 b) {
  half8 r;
  r[0] = (_Float16)a.x; r[1] = (_Float16)a.y; r[2] = (_Float16)a.z; r[3] = (_Float16)a.w;
  r[4] = (_Float16)b.x; r[5] = (_Float16)b.y; r[6] = (_Float16)b.z; r[7] = (_Float16)b.w;
  return r;
}

// ---------------------------------------------------------------------------
// f16 MFMA GEMM: C = oscale*(A @ W^T) + bias, then ACT. M = 4096 (full tiles).
// A: [M][K] row-major, fp32 (AF16=0) or f16 (AF16=1), leading dim lda.
// W: [N][K] fp32 row-major (converted to f16 in staging).
// C: TC=0 -> [M][N] ldc ; TC=1 -> [N][M] ldc. fp32 (OF16=0) or f16 (OF16=1).
// ACT: 0 none, 1 softplus, 2 silu. Block 256 thr = 4 waves; tile 128 x BN,
// BK=32 (one mfma_16x16x32 k-step). Wave tile 64 x BN/2.
// MFMA layouts (m89/m120-verified): A-frag A[m=lane&15][k=q*8+j],
// B-frag B[k=q*8+j][n=lane&15] (= W row n, k-run), D: col(n)=lane&15, row(m)=q*4+r.
// R7 FIX: A staging loads now include m0 (was reading tile 0 for every block).
// ---------------------------------------------------------------------------
template<int AF16, int BN, int TC, int ACT, int OF16>
__global__ __launch_bounds__(256)
void gemm_mfma(const void* __restrict__ Av, int lda,
               const float* __restrict__ W,
               const float* __restrict__ bias,
               void* __restrict__ Cv, int ldc,
               int N, int K, float oscale)
{
  constexpr int NF = BN / 32;            // n-frags per wave
  __shared__ _Float16 As[128 * 40];      // [m][k], row stride 40 f16 (80 B)
  __shared__ _Float16 Ws[BN * 40];       // [n][k]
  const int tid  = threadIdx.x;
  const int lane = tid & 63;
  const int wid  = tid >> 6;
  const int wm   = wid & 1, wn = wid >> 1;
  const int m0   = blockIdx.y * 128;
  const int n0   = blockIdx.x * BN;
  const int q    = lane >> 4, l16 = lane & 15;

  // staging coords
  const int ar  = tid >> 1;              // A: 2 threads/row, 16 k each
  const int akq = (tid & 1) * 16;
  const int wr  = (BN == 128) ? (tid >> 1) : (tid >> 2);
  const int wkq = (BN == 128) ? ((tid & 1) * 16) : ((tid & 3) * 8);
  const int wrow = n0 + wr;
  const bool wv  = (wrow < N);

  const float*    Af = (const float*)Av;
  const _Float16* Ah = (const _Float16*)Av;
  const float*    Wp = W + (size_t)wrow * K;
  const size_t aoff = (size_t)(m0 + ar) * lda + akq;   // R7: m0 included!

  float4 raf[4]; half8 rah[2]; float4 rwf[4];
  const float4 zf4 = make_float4(0.f, 0.f, 0.f, 0.f);

  // initial loads (k0 = 0)
  if (AF16) {
    const _Float16* p = Ah + aoff;
    rah[0] = *(const half8*)p; rah[1] = *(const half8*)(p + 8);
  } else {
    const float* p = Af + aoff;
    raf[0] = *(const float4*)p;       raf[1] = *(const float4*)(p + 4);
    raf[2] = *(const float4*)(p + 8); raf[3] = *(const float4*)(p + 12);
  }
  if (BN == 128) {
    if (wv) {
      const float* p = Wp + wkq;
      rwf[0] = *(const float4*)p;       rwf[1] = *(const float4*)(p + 4);
      rwf[2] = *(const float4*)(p + 8); rwf[3] = *(const float4*)(p + 12);
    } else { rwf[0] = rwf[1] = rwf[2] = rwf[3] = zf4; }
  } else {
    if (wv) {
      const float* p = Wp + wkq;
      rwf[0] = *(const float4*)p; rwf[1] = *(const float4*)(p + 4);
    } else { rwf[0] = rwf[1] = zf4; }
  }

  f32x4 acc[4][NF];
  #pragma unroll
  for (int mi = 0; mi < 4; ++mi)
    #pragma unroll
    for (int ni = 0; ni < NF; ++ni)
      acc[mi][ni] = (f32x4){0.f, 0.f, 0.f, 0.f};

  for (int k0 = 0; k0 < K; k0 += 32) {
    if (k0) __syncthreads();
    if (AF16) {
      *(half8*)&As[ar * 40 + akq]     = rah[0];
      *(half8*)&As[ar * 40 + akq + 8] = rah[1];
    } else {
      *(half8*)&As[ar * 40 + akq]     = pack_f16(raf[0], raf[1]);
      *(half8*)&As[ar * 40 + akq + 8] = pack_f16(raf[2], raf[3]);
    }
    if (BN == 128) {
      *(half8*)&Ws[wr * 40 + wkq]     = pack_f16(rwf[0], rwf[1]);
      *(half8*)&Ws[wr * 40 + wkq + 8] = pack_f16(rwf[2], rwf[3]);
    } else {
      *(half8*)&Ws[wr * 40 + wkq]     = pack_f16(rwf[0], rwf[1]);
    }
    __syncthreads();

    if (k0 + 32 < K) {            // prefetch next chunk (in flight over MFMAs)
      const int kn = k0 + 32;
      if (AF16) {
        const _Float16* p = Ah + aoff + kn;
        rah[0] = *(const half8*)p; rah[1] = *(const half8*)(p + 8);
      } else {
        const float* p = Af + aoff + kn;
        raf[0] = *(const float4*)p;       raf[1] = *(const float4*)(p + 4);
        raf[2] = *(const float4*)(p + 8); raf[3] = *(const float4*)(p + 12);
      }
      if (BN == 128) {
        if (wv) {
          const float* p = Wp + kn + wkq;
          rwf[0] = *(const float4*)p;       rwf[1] = *(const float4*)(p + 4);
          rwf[2] = *(const float4*)(p + 8); rwf[3] = *(const float4*)(p + 12);
        }
      } else {
        if (wv) {
          const float* p = Wp + kn + wkq;
          rwf[0] = *(const float4*)p; rwf[1] = *(const float4*)(p + 4);
        }
      }
    }

    half8 af[4], wf[NF];
    #pragma unroll
    for (int mi = 0; mi < 4; ++mi)
      af[mi] = *(const half8*)&As[(wm * 64 + mi * 16 + l16) * 40 + q * 8];
    #pragma unroll
    for (int ni = 0; ni < NF; ++ni)
      wf[ni] = *(const half8*)&Ws[(wn * (BN / 2) + ni * 16 + l16) * 40 + q * 8];
    #pragma unroll
    for (int mi = 0; mi < 4; ++mi)
      #pragma unroll
      for (int ni = 0; ni < NF; ++ni)
        acc[mi][ni] = __builtin_amdgcn_mfma_f32_16x16x32_f16(af[mi], wf[ni],
                                                             acc[mi][ni], 0, 0, 0);
  }

  // epilogue
  float*    Cf = (float*)Cv;
  _Float16* Ch = (_Float16*)Cv;
  #pragma unroll
  for (int ni = 0; ni < NF; ++ni) {
    const int n = n0 + wn * (BN / 2) + ni * 16 + l16;
    if (n < N) {
      const float bv = (bias != nullptr) ? bias[n] : 0.f;
      #pragma unroll
      for (int mi = 0; mi < 4; ++mi) {
        const int mb = m0 + wm * 64 + mi * 16 + q * 4;
        float o[4];
        #pragma unroll
        for (int r = 0; r < 4; ++r) {
          float v = acc[mi][ni][r] * oscale + bv;
          if (ACT == 1) v = (v > 20.f) ? v : log1pf(__expf(v));
          if (ACT == 2) v = silu_f(v);
          o[r] = v;
        }
        if (TC == 0) {
          #pragma unroll
          for (int r = 0; r < 4; ++r) {
            size_t off = (size_t)(mb + r) * ldc + n;
            if (OF16) Ch[off] = (_Float16)o[r];
            else      Cf[off] = o[r];
          }
        } else {
          size_t off = (size_t)n * ldc + mb;
          if (OF16) {
            half4v h4; h4[0]=(_Float16)o[0]; h4[1]=(_Float16)o[1];
                       h4[2]=(_Float16)o[2]; h4[3]=(_Float16)o[3];
            *(half4v*)&Ch[off] = h4;
          } else {
            *(float4*)&Cf[off] = make_float4(o[0], o[1], o[2], o[3]);
          }
        }
      }
    }
  }
}

// ---------------------------------------------------------------------------
// Depthwise causal conv (D_CONV=2) + silu, 64x64 LDS transpose.
// in : xcp [4096 bl][1024 d] fp32
// out: xcT [1024 d][4096 bl] fp32 (scan input)  +  xcf [4096 bl][1024 d] f16
// ---------------------------------------------------------------------------
__global__ void conv_t_kernel(const float* __restrict__ xcp,
                              const float* __restrict__ cw,   // [1024][2]
                              const float* __restrict__ cb,   // [1024]
                              float* __restrict__ xcT,
                              _Float16* __restrict__ xcf)
{
  __shared__ float tile[64][65];
  const int blk = blockIdx.x;            // b*256 + tt*16 + dd
  const int b  = blk >> 8;
  const int tt = (blk >> 4) & 15;
  const int dd = blk & 15;
  const int t0 = tt * 64, d0 = dd * 64;
  const int tid = threadIdx.x;

  #pragma unroll
  for (int i = 0; i < 16; ++i) {
    int idx = i * 256 + tid;
    int t = idx >> 6, d = idx & 63;
    int gt = t0 + t;
    size_t rcur = ((size_t)(b * 1024 + gt) << 10) + d0 + d;
    float cur  = xcp[rcur];
    float prev = (gt > 0) ? xcp[rcur - 1024] : 0.f;
    float v = fmaf(prev, cw[(d0+d)*2], fmaf(cur, cw[(d0+d)*2 + 1], cb[d0+d]));
    float sv = silu_f(v);
    tile[t][d] = sv;
    xcf[rcur] = (_Float16)sv;
  }
  __syncthreads();
  #pragma unroll
  for (int i = 0; i < 16; ++i) {
    int idx = i * 256 + tid;
    int d = idx >> 6, t = idx & 63;
    xcT[((size_t)(d0 + d) << 12) + b * 1024 + t0 + t] = tile[t][d];
  }
}

// ---------------------------------------------------------------------------
// Transpose + f16 convert WITH 2^14 scaling:
// src [1024 d][4096 bl] fp32 -> dst [4096 bl][1024 d] f16, dst = src * 16384.
// (layer-2 gated y ~1e-7 would flush to f16 subnormals unscaled)
// ---------------------------------------------------------------------------
__global__ void trans_f16_kernel(const float* __restrict__ src,
                                 _Float16* __restrict__ dst)
{
  __shared__ float tile[64][65];
  const int bl0 = blockIdx.x * 64;
  const int d0  = blockIdx.y * 64;
  const int tid = threadIdx.x;
  #pragma unroll
  for (int i = 0; i < 16; ++i) {
    int idx = i * 256 + tid;
    int r = idx >> 6, c = idx & 63;     // r: d, c: bl
    tile[r][c] = src[((size_t)(d0 + r) << 12) + bl0 + c];
  }
  __syncthreads();
  #pragma unroll
  for (int i = 0; i < 16; ++i) {
    int idx = i * 256 + tid;
    int c = idx >> 6, r = idx & 63;     // write rows bl, cols d
    dst[((size_t)(bl0 + c) << 10) + d0 + r] = (_Float16)(tile[r][c] * Y_SCALE);
  }
}

// ---------------------------------------------------------------------------
// Selective scan, time-major. One wave per (b,d), lane = s (D_STATE=64).
// y = (scan + x*Dp) * silu(z) written IN PLACE over xcT.
// ---------------------------------------------------------------------------
__global__ __launch_bounds__(256, 4)
void scan_kernel(const float* __restrict__ dtT,     // [1024][4096]
                 float* __restrict__ xcT,           // [1024][4096]; y in place
                 const _Float16* __restrict__ zsT,  // [1024][4096], silu(z), f16
                 const float* __restrict__ dbc,     // [B][1024][160]; B@+32, C@+96
                 const float* __restrict__ A_log,   // [1024][64]
                 const float* __restrict__ Dp)      // [1024]
{
  __shared__ float P[4][16][68];
  const int lane = threadIdx.x & 63;
  const int wrp  = threadIdx.x >> 6;
  const int wid  = __builtin_amdgcn_readfirstlane(blockIdx.x * 4 + wrp);
  const int b = wid >> 10;
  const int d = wid & 1023;
  float (*Pw)[68] = P[wrp];

  const float a   = -__expf(A_log[d*64 + lane]);
  const float dpv = Dp[d];
  const size_t row = ((size_t)d << 12) + b * 1024;
  const float*    dtp = dtT + row;
  float*          xyp = xcT + row;
  const _Float16* zsp = zsT + row;
  const float*    bcp = dbc + (size_t)b * 163840 + lane;

  const int tt_r = lane >> 2;
  const int c0   = (lane & 3) << 4;

  float h = 0.f;
  for (int t0 = 0; t0 < 1024; t0 += 16) {
    float4 dq[4], xq[4];
    #pragma unroll
    for (int i = 0; i < 4; ++i) {
      dq[i] = *(const float4*)(dtp + t0 + i*4);
      xq[i] = *(const float4*)(xyp + t0 + i*4);
    }
    const float* dtv = reinterpret_cast<const float*>(dq);
    const float* xv  = reinterpret_cast<const float*>(xq);
    float zs = (float)zsp[t0 + tt_r];
    float Bv[16], Cv[16];
    #pragma unroll
    for (int tt = 0; tt < 16; ++tt) {
      Bv[tt] = bcp[(size_t)(t0 + tt) * 160 + 32];
      Cv[tt] = bcp[(size_t)(t0 + tt) * 160 + 96];
    }
    #pragma unroll
    for (int tt = 0; tt < 16; ++tt) {
      float dA = __expf(dtv[tt] * a);
      h = fmaf(h, dA, dtv[tt] * xv[tt] * Bv[tt]);
      float p = h * Cv[tt];
      if (lane == tt) p = fmaf(xv[tt], dpv, p);
      Pw[tt][lane] = p;
    }
    float4 s0 = *(const float4*)&Pw[tt_r][c0];
    float4 s1 = *(const float4*)&Pw[tt_r][c0 + 4];
    float4 s2 = *(const float4*)&Pw[tt_r][c0 + 8];
    float4 s3 = *(const float4*)&Pw[tt_r][c0 + 12];
    float r = ((s0.x + s0.y) + (s0.z + s0.w))
            + ((s1.x + s1.y) + (s1.z + s1.w))
            + ((s2.x + s2.y) + (s2.z + s2.w))
            + ((s3.x + s3.y) + (s3.z + s3.w));
    r += __shfl_xor(r, 1, 64);
    r += __shfl_xor(r, 2, 64);
    if ((lane & 3) == 0)
      xyp[t0 + tt_r] = r * zs;
  }
}

// out[b,c] = h[b,L-1,:] . fc_w[c,:] + fc_b[c]; h is fp32 [4096][512]
__global__ void head_kernel(const float* __restrict__ h,
                            const float* __restrict__ fc_w,
                            const float* __restrict__ fc_b,
                            float* __restrict__ out)
{
  int bc = blockIdx.x;            // 0..11
  int b = bc / 3, c = bc % 3;
  int lane = threadIdx.x;
  const float* hr = h + (size_t)(b*1024 + 1023) * 512;
  const float* wr = fc_w + c*512;
  float s = 0.f;
  #pragma unroll
  for (int i = 0; i < 8; ++i) s = fmaf(hr[lane + i*64], wr[lane + i*64], s);
  #pragma unroll
  for (int o = 32; o > 0; o >>= 1) s += __shfl_xor(s, o, 64);
  if (lane == 0) out[b*3 + c] = s + fc_b[c];
}

extern "C" void kernel_launch(void* const* d_in, const int* in_sizes, int n_in,
                              void* d_out, int out_size, void* d_ws, size_t ws_size,
                              hipStream_t stream)
{
  const float* x        = (const float*)d_in[0];
  const float* exp_w    = (const float*)d_in[1];
  const float* exp_b    = (const float*)d_in[2];
  const float* in_w     = (const float*)d_in[3];
  const float* conv_w   = (const float*)d_in[4];
  const float* conv_b   = (const float*)d_in[5];
  const float* xproj_w  = (const float*)d_in[6];
  const float* dtproj_w = (const float*)d_in[7];
  const float* dtproj_b = (const float*)d_in[8];
  const float* A_log    = (const float*)d_in[9];
  const float* Dp       = (const float*)d_in[10];
  const float* out_w    = (const float*)d_in[11];
  const float* fc_w     = (const float*)d_in[12];
  const float* fc_b     = (const float*)d_in[13];
  float* out = (float*)d_out;

  // Workspace layout (byte offsets), 59 MB total. The 8..24 MB region is
  // sequentially reused: xcpre (in_proj -> conv_t) -> dtT (dtproj -> scan)
  // -> y16 (trans_f16 -> out_proj).
  char* ws = (char*)d_ws;
  float*    hf    = (float*)   (ws);                          //  8 MB [4096][512] fp32
  float*    xcpre = (float*)   (ws + ((size_t)8  << 20));     // 16 MB [4096][1024]
  float*    dtT   = (float*)   (ws + ((size_t)8  << 20));     // 16 MB [1024][4096] (reuse)
  _Float16* y16   = (_Float16*)(ws + ((size_t)8  << 20));     //  8 MB [4096][1024] (reuse)
  float*    xcT   = (float*)   (ws + ((size_t)24 << 20));     // 16 MB [1024][4096]
  _Float16* zsT   = (_Float16*)(ws + ((size_t)40 << 20));     //  8 MB [1024][4096]
  float*    dbc   = (float*)   (ws + ((size_t)48 << 20));     //  2.6 MB [4096][160]
  _Float16* xc16  = (_Float16*)(ws + ((size_t)51 << 20));     //  8 MB [4096][1024]

  dim3 blk(256);

  // expand: hf = x @ exp_w^T + exp_b   [4096,512] K=128, fp32 out
  gemm_mfma<0,128,0,0,0><<<dim3(4,32), blk, 0, stream>>>(x, 128, exp_w, exp_b,
                                                         hf, 512, 512, 128, 1.f);

  for (int l = 0; l < 2; ++l) {
    const float* inw = in_w + (size_t)l * 2048 * 512;
    // in_proj xc half: xcpre = h @ in_w[0:1024]^T   [4096,1024] K=512
    gemm_mfma<0,128,0,0,0><<<dim3(8,32), blk, 0, stream>>>(hf, 512, inw, nullptr,
                                                           xcpre, 1024, 1024, 512, 1.f);
    // in_proj z half (transposed + silu + f16): zsT [1024][4096]
    gemm_mfma<0,128,1,2,1><<<dim3(8,32), blk, 0, stream>>>(hf, 512, inw + (size_t)1024*512,
                                                           nullptr, zsT, 4096, 1024, 512, 1.f);
    // conv + silu -> xcT (fp32, scan) + xc16 (f16, xproj A)
    conv_t_kernel<<<1024, blk, 0, stream>>>(xcpre, conv_w + l*2048, conv_b + l*1024,
                                            xcT, xc16);
    // xproj: dbc = xc @ xproj_w^T   [4096,160] K=1024
    gemm_mfma<1,64,0,0,0><<<dim3(3,32), blk, 0, stream>>>(xc16, 1024,
                                                          xproj_w + (size_t)l*160*1024,
                                                          nullptr, dbc, 160, 160, 1024, 1.f);
    // dtproj (transposed + softplus): dtT [1024][4096], K=32 (overwrites xcpre — dead)
    gemm_mfma<0,128,1,1,0><<<dim3(8,32), blk, 0, stream>>>(dbc, 160,
                                                           dtproj_w + (size_t)l*1024*32,
                                                           dtproj_b + l*1024,
                                                           dtT, 4096, 1024, 32, 1.f);
    // selective scan; y = (scan + x*Dp)*silu(z) over xcT
    scan_kernel<<<1024, blk, 0, stream>>>(dtT, xcT, zsT, dbc,
                                          A_log + (size_t)l*65536, Dp + l*1024);
    // y -> y16 = f16(y * 2^14) [4096][1024]   (overwrites dtT — dead)
    trans_f16_kernel<<<dim3(64,16), blk, 0, stream>>>(xcT, y16);
    // out_proj: hf = (y16 @ out_w^T) * 2^-14   [4096,512] K=1024, fp32 out
    gemm_mfma<1,64,0,0,0><<<dim3(8,32), blk, 0, stream>>>(y16, 1024,
                                                          out_w + (size_t)l*512*1024,
                                                          nullptr, hf, 512, 512, 1024,
                                                          1.f / Y_SCALE);
  }

  head_kernel<<<12, 64, 0, stream>>>(hf, fc_w, fc_b, out);
}

// Round 8
// 554.418 us; speedup vs baseline: 3.2280x; 1.0423x over previous
//
#include <hip/hip_runtime.h>
#include <math.h>

// Problem constants: B=4, L=1024, D_IN=128, D_MODEL=512, N_LAYERS=2,
// N_CLASSES=3, D_INNER=1024, D_STATE=64, D_CONV=2, DT_RANK=32, BL=4096.
//
// Precision plan (values shrink ~1000x per layer; final output ~3e-8):
//  - residual h kept fp32 end-to-end (layer-2 h ~3e-8 is f16-subnormal).
//  - y (out_proj A operand) scaled by 2^14 before f16 conversion; out_proj
//    epilogue multiplies by 2^-14 (exact powers of two).

using half8  = __attribute__((ext_vector_type(8))) _Float16;
using half4v = __attribute__((ext_vector_type(4))) _Float16;
using f32x4  = __attribute__((ext_vector_type(4))) float;

#define Y_SCALE 16384.0f   // 2^14

__device__ __forceinline__ float silu_f(float v) {
  return v / (1.f + __expf(-v));
}

__device__ __forceinline__ half8 pack_f16(float4 a, float4 b) {
  half8 r;
  r[0] = (_Float16)a.x; r[1] = (_Float16)a.y; r[2] = (_Float16)a.z; r[3] = (_Float16)a.w;
  r[4] = (_Float16)b.x; r[5] = (_Float16)b.y; r[6] = (_Float16)b.z; r[7] = (_Float16)b.w;
  return r;
}

// ---------------------------------------------------------------------------
// f16 MFMA GEMM: C = oscale*(A @ W^T) + bias, then ACT. M = 4096 (full tiles).
// A: [M][K] row-major, fp32 (AF16=0) or f16 (AF16=1), leading dim lda.
// W: [N][K] fp32 row-major (converted to f16 in staging).
// MODE 0: C per TC/ACT/OF16 (TC=0 -> [M][N]; TC=1 -> [N][M]).
// MODE 1 (fused in_proj, N=2048): n<1024 -> Cv fp32 [M][1024];
//        n>=1024 -> Cv2 f16 silu transposed [n-1024][4096].
// Block 256 thr = 4 waves; tile 128 x BN, BK=32. Wave tile 64 x BN/2.
// MFMA layouts (m89/m120-verified): A-frag A[m=lane&15][k=q*8+j],
// B-frag B[k=q*8+j][n=lane&15], D: col(n)=lane&15, row(m)=q*4+r.
// ---------------------------------------------------------------------------
template<int AF16, int BN, int TC, int ACT, int OF16, int MODE>
__global__ __launch_bounds__(256)
void gemm_mfma(const void* __restrict__ Av, int lda,
               const float* __restrict__ W,
               const float* __restrict__ bias,
               void* __restrict__ Cv, int ldc,
               int N, int K, float oscale,
               void* __restrict__ Cv2)
{
  constexpr int NF = BN / 32;            // n-frags per wave
  __shared__ _Float16 As[128 * 40];      // [m][k], row stride 40 f16 (80 B)
  __shared__ _Float16 Ws[BN * 40];       // [n][k]
  const int tid  = threadIdx.x;
  const int lane = tid & 63;
  const int wid  = tid >> 6;
  const int wm   = wid & 1, wn = wid >> 1;
  const int m0   = blockIdx.y * 128;
  const int n0   = blockIdx.x * BN;
  const int q    = lane >> 4, l16 = lane & 15;

  // staging coords
  const int ar  = tid >> 1;              // A: 2 threads/row, 16 k each
  const int akq = (tid & 1) * 16;
  const int wr  = (BN == 128) ? (tid >> 1) : (tid >> 2);
  const int wkq = (BN == 128) ? ((tid & 1) * 16) : ((tid & 3) * 8);
  const int wrow = n0 + wr;
  const bool wv  = (wrow < N);

  const float*    Af = (const float*)Av;
  const _Float16* Ah = (const _Float16*)Av;
  const float*    Wp = W + (size_t)wrow * K;
  const size_t aoff = (size_t)(m0 + ar) * lda + akq;   // m0 included (R7 fix)

  float4 raf[4]; half8 rah[2]; float4 rwf[4];
  const float4 zf4 = make_float4(0.f, 0.f, 0.f, 0.f);

  // initial loads (k0 = 0)
  if (AF16) {
    const _Float16* p = Ah + aoff;
    rah[0] = *(const half8*)p; rah[1] = *(const half8*)(p + 8);
  } else {
    const float* p = Af + aoff;
    raf[0] = *(const float4*)p;       raf[1] = *(const float4*)(p + 4);
    raf[2] = *(const float4*)(p + 8); raf[3] = *(const float4*)(p + 12);
  }
  if (BN == 128) {
    if (wv) {
      const float* p = Wp + wkq;
      rwf[0] = *(const float4*)p;       rwf[1] = *(const float4*)(p + 4);
      rwf[2] = *(const float4*)(p + 8); rwf[3] = *(const float4*)(p + 12);
    } else { rwf[0] = rwf[1] = rwf[2] = rwf[3] = zf4; }
  } else {
    if (wv) {
      const float* p = Wp + wkq;
      rwf[0] = *(const float4*)p; rwf[1] = *(const float4*)(p + 4);
    } else { rwf[0] = rwf[1] = zf4; }
  }

  f32x4 acc[4][NF];
  #pragma unroll
  for (int mi = 0; mi < 4; ++mi)
    #pragma unroll
    for (int ni = 0; ni < NF; ++ni)
      acc[mi][ni] = (f32x4){0.f, 0.f, 0.f, 0.f};

  for (int k0 = 0; k0 < K; k0 += 32) {
    if (k0) __syncthreads();
    if (AF16) {
      *(half8*)&As[ar * 40 + akq]     = rah[0];
      *(half8*)&As[ar * 40 + akq + 8] = rah[1];
    } else {
      *(half8*)&As[ar * 40 + akq]     = pack_f16(raf[0], raf[1]);
      *(half8*)&As[ar * 40 + akq + 8] = pack_f16(raf[2], raf[3]);
    }
    if (BN == 128) {
      *(half8*)&Ws[wr * 40 + wkq]     = pack_f16(rwf[0], rwf[1]);
      *(half8*)&Ws[wr * 40 + wkq + 8] = pack_f16(rwf[2], rwf[3]);
    } else {
      *(half8*)&Ws[wr * 40 + wkq]     = pack_f16(rwf[0], rwf[1]);
    }
    __syncthreads();

    if (k0 + 32 < K) {            // prefetch next chunk (in flight over MFMAs)
      const int kn = k0 + 32;
      if (AF16) {
        const _Float16* p = Ah + aoff + kn;
        rah[0] = *(const half8*)p; rah[1] = *(const half8*)(p + 8);
      } else {
        const float* p = Af + aoff + kn;
        raf[0] = *(const float4*)p;       raf[1] = *(const float4*)(p + 4);
        raf[2] = *(const float4*)(p + 8); raf[3] = *(const float4*)(p + 12);
      }
      if (BN == 128) {
        if (wv) {
          const float* p = Wp + kn + wkq;
          rwf[0] = *(const float4*)p;       rwf[1] = *(const float4*)(p + 4);
          rwf[2] = *(const float4*)(p + 8); rwf[3] = *(const float4*)(p + 12);
        }
      } else {
        if (wv) {
          const float* p = Wp + kn + wkq;
          rwf[0] = *(const float4*)p; rwf[1] = *(const float4*)(p + 4);
        }
      }
    }

    half8 af[4], wf[NF];
    #pragma unroll
    for (int mi = 0; mi < 4; ++mi)
      af[mi] = *(const half8*)&As[(wm * 64 + mi * 16 + l16) * 40 + q * 8];
    #pragma unroll
    for (int ni = 0; ni < NF; ++ni)
      wf[ni] = *(const half8*)&Ws[(wn * (BN / 2) + ni * 16 + l16) * 40 + q * 8];
    #pragma unroll
    for (int mi = 0; mi < 4; ++mi)
      #pragma unroll
      for (int ni = 0; ni < NF; ++ni)
        acc[mi][ni] = __builtin_amdgcn_mfma_f32_16x16x32_f16(af[mi], wf[ni],
                                                             acc[mi][ni], 0, 0, 0);
  }

  float*    Cf = (float*)Cv;
  _Float16* Ch = (_Float16*)Cv;

  if (MODE == 1) {
    // fused in_proj epilogue: branch is block-uniform (BN=128 divides 1024)
    _Float16* Ch2 = (_Float16*)Cv2;
    #pragma unroll
    for (int ni = 0; ni < NF; ++ni) {
      const int n = n0 + wn * (BN / 2) + ni * 16 + l16;
      if (n < 1024) {
        #pragma unroll
        for (int mi = 0; mi < 4; ++mi) {
          const int mb = m0 + wm * 64 + mi * 16 + q * 4;
          #pragma unroll
          for (int r = 0; r < 4; ++r)
            Cf[(size_t)(mb + r) * 1024 + n] = acc[mi][ni][r];
        }
      } else {
        const int nn = n - 1024;
        #pragma unroll
        for (int mi = 0; mi < 4; ++mi) {
          const int mb = m0 + wm * 64 + mi * 16 + q * 4;
          half4v h4;
          #pragma unroll
          for (int r = 0; r < 4; ++r) h4[r] = (_Float16)silu_f(acc[mi][ni][r]);
          *(half4v*)&Ch2[(size_t)nn * 4096 + mb] = h4;
        }
      }
    }
    return;
  }

  // MODE 0 epilogue
  #pragma unroll
  for (int ni = 0; ni < NF; ++ni) {
    const int n = n0 + wn * (BN / 2) + ni * 16 + l16;
    if (n < N) {
      const float bv = (bias != nullptr) ? bias[n] : 0.f;
      #pragma unroll
      for (int mi = 0; mi < 4; ++mi) {
        const int mb = m0 + wm * 64 + mi * 16 + q * 4;
        float o[4];
        #pragma unroll
        for (int r = 0; r < 4; ++r) {
          float v = acc[mi][ni][r] * oscale + bv;
          if (ACT == 1) v = (v > 20.f) ? v : log1pf(__expf(v));
          if (ACT == 2) v = silu_f(v);
          o[r] = v;
        }
        if (TC == 0) {
          #pragma unroll
          for (int r = 0; r < 4; ++r) {
            size_t off = (size_t)(mb + r) * ldc + n;
            if (OF16) Ch[off] = (_Float16)o[r];
            else      Cf[off] = o[r];
          }
        } else {
          size_t off = (size_t)n * ldc + mb;
          if (OF16) {
            half4v h4; h4[0]=(_Float16)o[0]; h4[1]=(_Float16)o[1];
                       h4[2]=(_Float16)o[2]; h4[3]=(_Float16)o[3];
            *(half4v*)&Ch[off] = h4;
          } else {
            *(float4*)&Cf[off] = make_float4(o[0], o[1], o[2], o[3]);
          }
        }
      }
    }
  }
}

// ---------------------------------------------------------------------------
// Depthwise causal conv (D_CONV=2) + silu, 64x64 LDS transpose.
// in : xcp [4096 bl][1024 d] fp32
// out: xcT [1024 d][4096 bl] fp32 (scan input)  +  xcf [4096 bl][1024 d] f16
// ---------------------------------------------------------------------------
__global__ void conv_t_kernel(const float* __restrict__ xcp,
                              const float* __restrict__ cw,   // [1024][2]
                              const float* __restrict__ cb,   // [1024]
                              float* __restrict__ xcT,
                              _Float16* __restrict__ xcf)
{
  __shared__ float tile[64][65];
  const int blk = blockIdx.x;            // b*256 + tt*16 + dd
  const int b  = blk >> 8;
  const int tt = (blk >> 4) & 15;
  const int dd = blk & 15;
  const int t0 = tt * 64, d0 = dd * 64;
  const int tid = threadIdx.x;

  #pragma unroll
  for (int i = 0; i < 16; ++i) {
    int idx = i * 256 + tid;
    int t = idx >> 6, d = idx & 63;
    int gt = t0 + t;
    size_t rcur = ((size_t)(b * 1024 + gt) << 10) + d0 + d;
    float cur  = xcp[rcur];
    float prev = (gt > 0) ? xcp[rcur - 1024] : 0.f;
    float v = fmaf(prev, cw[(d0+d)*2], fmaf(cur, cw[(d0+d)*2 + 1], cb[d0+d]));
    float sv = silu_f(v);
    tile[t][d] = sv;
    xcf[rcur] = (_Float16)sv;
  }
  __syncthreads();
  #pragma unroll
  for (int i = 0; i < 16; ++i) {
    int idx = i * 256 + tid;
    int d = idx >> 6, t = idx & 63;
    xcT[((size_t)(d0 + d) << 12) + b * 1024 + t0 + t] = tile[t][d];
  }
}

// ---------------------------------------------------------------------------
// Transpose + f16 convert WITH 2^14 scaling:
// src [1024 d][4096 bl] fp32 -> dst [4096 bl][1024 d] f16, dst = src * 16384.
// ---------------------------------------------------------------------------
__global__ void trans_f16_kernel(const float* __restrict__ src,
                                 _Float16* __restrict__ dst)
{
  __shared__ float tile[64][65];
  const int bl0 = blockIdx.x * 64;
  const int d0  = blockIdx.y * 64;
  const int tid = threadIdx.x;
  #pragma unroll
  for (int i = 0; i < 16; ++i) {
    int idx = i * 256 + tid;
    int r = idx >> 6, c = idx & 63;     // r: d, c: bl
    tile[r][c] = src[((size_t)(d0 + r) << 12) + bl0 + c];
  }
  __syncthreads();
  #pragma unroll
  for (int i = 0; i < 16; ++i) {
    int idx = i * 256 + tid;
    int c = idx >> 6, r = idx & 63;     // write rows bl, cols d
    dst[((size_t)(bl0 + c) << 10) + d0 + r] = (_Float16)(tile[r][c] * Y_SCALE);
  }
}

// ---------------------------------------------------------------------------
// Selective scan, time-major. One wave per (b,d), lane = s (D_STATE=64).
// VALU diet (R8): a2 = a*log2e precomputed (exp2 instead of exp+mul);
// u = dt*x hoisted to the load phase; the per-t `lane==tt` fold of x*Dp is
// replaced by one per-lane load of x[tt_r] + post-reduction fma.
// y = (scan + x*Dp) * silu(z) written IN PLACE over xcT.
// ---------------------------------------------------------------------------
__global__ __launch_bounds__(256, 4)
void scan_kernel(const float* __restrict__ dtT,     // [1024][4096]
                 float* __restrict__ xcT,           // [1024][4096]; y in place
                 const _Float16* __restrict__ zsT,  // [1024][4096], silu(z), f16
                 const float* __restrict__ dbc,     // [B][1024][160]; B@+32, C@+96
                 const float* __restrict__ A_log,   // [1024][64]
                 const float* __restrict__ Dp)      // [1024]
{
  __shared__ float P[4][16][68];
  const int lane = threadIdx.x & 63;
  const int wrp  = threadIdx.x >> 6;
  const int wid  = __builtin_amdgcn_readfirstlane(blockIdx.x * 4 + wrp);
  const int b = wid >> 10;
  const int d = wid & 1023;
  float (*Pw)[68] = P[wrp];

  const float a2  = -__expf(A_log[d*64 + lane]) * 1.44269504f;  // a * log2(e)
  const float dpv = Dp[d];
  const size_t row = ((size_t)d << 12) + b * 1024;
  const float*    dtp = dtT + row;
  float*          xyp = xcT + row;
  const _Float16* zsp = zsT + row;
  const float*    bcp = dbc + (size_t)b * 163840 + lane;

  const int tt_r = lane >> 2;          // which timestep this lane reduces
  const int c0   = (lane & 3) << 4;    // which 16-state chunk

  float h = 0.f;
  for (int t0 = 0; t0 < 1024; t0 += 16) {
    // ---- load phase (independent; overlaps recurrence latency) ----
    float4 dq[4], xq[4];
    #pragma unroll
    for (int i = 0; i < 4; ++i) {
      dq[i] = *(const float4*)(dtp + t0 + i*4);
      xq[i] = *(const float4*)(xyp + t0 + i*4);
    }
    float zs  = (float)zsp[t0 + tt_r];
    float xvl = xyp[t0 + tt_r];          // this lane's x (read before y store)
    float Bv[16], Cv[16];
    #pragma unroll
    for (int tt = 0; tt < 16; ++tt) {
      Bv[tt] = bcp[(size_t)(t0 + tt) * 160 + 32];
      Cv[tt] = bcp[(size_t)(t0 + tt) * 160 + 96];
    }
    const float* dtv = reinterpret_cast<const float*>(dq);
    const float* xv  = reinterpret_cast<const float*>(xq);
    float u[16];
    #pragma unroll
    for (int tt = 0; tt < 16; ++tt) u[tt] = dtv[tt] * xv[tt];

    // ---- serial recurrence: exp2 -> fma -> mul per t ----
    #pragma unroll
    for (int tt = 0; tt < 16; ++tt) {
      float dA = __builtin_exp2f(dtv[tt] * a2);
      h = fmaf(h, dA, u[tt] * Bv[tt]);
      Pw[tt][lane] = h * Cv[tt];
    }

    // ---- batched reduction: lane L sums 16 states of timestep L>>2 ----
    float4 s0 = *(const float4*)&Pw[tt_r][c0];
    float4 s1 = *(const float4*)&Pw[tt_r][c0 + 4];
    float4 s2 = *(const float4*)&Pw[tt_r][c0 + 8];
    float4 s3 = *(const float4*)&Pw[tt_r][c0 + 12];
    float r = ((s0.x + s0.y) + (s0.z + s0.w))
            + ((s1.x + s1.y) + (s1.z + s1.w))
            + ((s2.x + s2.y) + (s2.z + s2.w))
            + ((s3.x + s3.y) + (s3.z + s3.w));
    r += __shfl_xor(r, 1, 64);
    r += __shfl_xor(r, 2, 64);
    if ((lane & 3) == 0)
      xyp[t0 + tt_r] = fmaf(xvl, dpv, r) * zs;
  }
}

// out[b,c] = h[b,L-1,:] . fc_w[c,:] + fc_b[c]; h is fp32 [4096][512]
__global__ void head_kernel(const float* __restrict__ h,
                            const float* __restrict__ fc_w,
                            const float* __restrict__ fc_b,
                            float* __restrict__ out)
{
  int bc = blockIdx.x;            // 0..11
  int b = bc / 3, c = bc % 3;
  int lane = threadIdx.x;
  const float* hr = h + (size_t)(b*1024 + 1023) * 512;
  const float* wr = fc_w + c*512;
  float s = 0.f;
  #pragma unroll
  for (int i = 0; i < 8; ++i) s = fmaf(hr[lane + i*64], wr[lane + i*64], s);
  #pragma unroll
  for (int o = 32; o > 0; o >>= 1) s += __shfl_xor(s, o, 64);
  if (lane == 0) out[b*3 + c] = s + fc_b[c];
}

extern "C" void kernel_launch(void* const* d_in, const int* in_sizes, int n_in,
                              void* d_out, int out_size, void* d_ws, size_t ws_size,
                              hipStream_t stream)
{
  const float* x        = (const float*)d_in[0];
  const float* exp_w    = (const float*)d_in[1];
  const float* exp_b    = (const float*)d_in[2];
  const float* in_w     = (const float*)d_in[3];
  const float* conv_w   = (const float*)d_in[4];
  const float* conv_b   = (const float*)d_in[5];
  const float* xproj_w  = (const float*)d_in[6];
  const float* dtproj_w = (const float*)d_in[7];
  const float* dtproj_b = (const float*)d_in[8];
  const float* A_log    = (const float*)d_in[9];
  const float* Dp       = (const float*)d_in[10];
  const float* out_w    = (const float*)d_in[11];
  const float* fc_w     = (const float*)d_in[12];
  const float* fc_b     = (const float*)d_in[13];
  float* out = (float*)d_out;

  // Workspace layout (byte offsets), 59 MB total. The 8..24 MB region is
  // sequentially reused: xcpre (in_proj -> conv_t) -> dtT (dtproj -> scan)
  // -> y16 (trans_f16 -> out_proj).
  char* ws = (char*)d_ws;
  float*    hf    = (float*)   (ws);                          //  8 MB [4096][512] fp32
  float*    xcpre = (float*)   (ws + ((size_t)8  << 20));     // 16 MB [4096][1024]
  float*    dtT   = (float*)   (ws + ((size_t)8  << 20));     // 16 MB [1024][4096] (reuse)
  _Float16* y16   = (_Float16*)(ws + ((size_t)8  << 20));     //  8 MB [4096][1024] (reuse)
  float*    xcT   = (float*)   (ws + ((size_t)24 << 20));     // 16 MB [1024][4096]
  _Float16* zsT   = (_Float16*)(ws + ((size_t)40 << 20));     //  8 MB [1024][4096]
  float*    dbc   = (float*)   (ws + ((size_t)48 << 20));     //  2.6 MB [4096][160]
  _Float16* xc16  = (_Float16*)(ws + ((size_t)51 << 20));     //  8 MB [4096][1024]

  dim3 blk(256);

  // expand: hf = x @ exp_w^T + exp_b   [4096,512] K=128, fp32 out
  gemm_mfma<0,128,0,0,0,0><<<dim3(4,32), blk, 0, stream>>>(x, 128, exp_w, exp_b,
                                                           hf, 512, 512, 128, 1.f, nullptr);

  for (int l = 0; l < 2; ++l) {
    const float* inw = in_w + (size_t)l * 2048 * 512;
    // fused in_proj: xcpre [4096][1024] f32 + zsT [1024][4096] silu f16, N=2048 K=512
    gemm_mfma<0,128,0,0,0,1><<<dim3(16,32), blk, 0, stream>>>(hf, 512, inw, nullptr,
                                                              xcpre, 1024, 2048, 512, 1.f,
                                                              zsT);
    // conv + silu -> xcT (fp32, scan) + xc16 (f16, xproj A)
    conv_t_kernel<<<1024, blk, 0, stream>>>(xcpre, conv_w + l*2048, conv_b + l*1024,
                                            xcT, xc16);
    // xproj: dbc = xc @ xproj_w^T   [4096,160] K=1024
    gemm_mfma<1,64,0,0,0,0><<<dim3(3,32), blk, 0, stream>>>(xc16, 1024,
                                                            xproj_w + (size_t)l*160*1024,
                                                            nullptr, dbc, 160, 160, 1024,
                                                            1.f, nullptr);
    // dtproj (transposed + softplus): dtT [1024][4096], K=32 (overwrites xcpre — dead)
    gemm_mfma<0,128,1,1,0,0><<<dim3(8,32), blk, 0, stream>>>(dbc, 160,
                                                             dtproj_w + (size_t)l*1024*32,
                                                             dtproj_b + l*1024,
                                                             dtT, 4096, 1024, 32, 1.f,
                                                             nullptr);
    // selective scan; y = (scan + x*Dp)*silu(z) over xcT
    scan_kernel<<<1024, blk, 0, stream>>>(dtT, xcT, zsT, dbc,
                                          A_log + (size_t)l*65536, Dp + l*1024);
    // y -> y16 = f16(y * 2^14) [4096][1024]   (overwrites dtT — dead)
    trans_f16_kernel<<<dim3(64,16), blk, 0, stream>>>(xcT, y16);
    // out_proj: hf = (y16 @ out_w^T) * 2^-14   [4096,512] K=1024, fp32 out
    gemm_mfma<1,64,0,0,0,0><<<dim3(8,32), blk, 0, stream>>>(y16, 1024,
                                                            out_w + (size_t)l*512*1024,
                                                            nullptr, hf, 512, 512, 1024,
                                                            1.f / Y_SCALE, nullptr);
  }

  head_kernel<<<12, 64, 0, stream>>>(hf, fc_w, fc_b, out);
}

// Round 9
// 533.835 us; speedup vs baseline: 3.3525x; 1.0386x over previous
//
#include <hip/hip_runtime.h>
#include <math.h>

// Problem constants: B=4, L=1024, D_IN=128, D_MODEL=512, N_LAYERS=2,
// N_CLASSES=3, D_INNER=1024, D_STATE=64, D_CONV=2, DT_RANK=32, BL=4096.
//
// Precision plan (values shrink ~1000x per layer; final output ~3e-8):
//  - residual h kept fp32 end-to-end (layer-2 h ~3e-8 is f16-subnormal).
//  - y (out_proj A operand) scaled by 2^14 before f16 conversion; out_proj
//    epilogue multiplies by 2^-14 (exact powers of two).

using half8  = __attribute__((ext_vector_type(8))) _Float16;
using half4v = __attribute__((ext_vector_type(4))) _Float16;
using f32x4  = __attribute__((ext_vector_type(4))) float;

#define Y_SCALE 16384.0f   // 2^14

__device__ __forceinline__ float silu_f(float v) {
  return v / (1.f + __expf(-v));
}

__device__ __forceinline__ half8 pack_f16(float4 a, float4 b) {
  half8 r;
  r[0] = (_Float16)a.x; r[1] = (_Float16)a.y; r[2] = (_Float16)a.z; r[3] = (_Float16)a.w;
  r[4] = (_Float16)b.x; r[5] = (_Float16)b.y; r[6] = (_Float16)b.z; r[7] = (_Float16)b.w;
  return r;
}

// ---------------------------------------------------------------------------
// f16 MFMA GEMM: C = oscale*(A @ W^T) + bias, then ACT. M = 4096 (full tiles).
// A: [M][K] row-major, fp32 (AF16=0) or f16 (AF16=1), leading dim lda.
// W: [N][K] fp32 row-major (converted to f16 in staging).
// MODE 0: C per TC/ACT/OF16 (TC=0 -> [M][N]; TC=1 -> [N][M]).
// MODE 1 (fused in_proj, N=2048): n<1024 -> Cv fp32 [M][1024];
//        n>=1024 -> Cv2 f16 silu transposed [n-1024][4096].
// Block 256 thr = 4 waves; tile 128 x BN, BK=32. Wave tile 64 x BN/2.
// MFMA layouts (m89/m120-verified): A-frag A[m=lane&15][k=q*8+j],
// B-frag B[k=q*8+j][n=lane&15], D: col(n)=lane&15, row(m)=q*4+r.
// ---------------------------------------------------------------------------
template<int AF16, int BN, int TC, int ACT, int OF16, int MODE>
__global__ __launch_bounds__(256)
void gemm_mfma(const void* __restrict__ Av, int lda,
               const float* __restrict__ W,
               const float* __restrict__ bias,
               void* __restrict__ Cv, int ldc,
               int N, int K, float oscale,
               void* __restrict__ Cv2)
{
  constexpr int NF = BN / 32;            // n-frags per wave
  __shared__ _Float16 As[128 * 40];      // [m][k], row stride 40 f16 (80 B)
  __shared__ _Float16 Ws[BN * 40];       // [n][k]
  const int tid  = threadIdx.x;
  const int lane = tid & 63;
  const int wid  = tid >> 6;
  const int wm   = wid & 1, wn = wid >> 1;
  const int m0   = blockIdx.y * 128;
  const int n0   = blockIdx.x * BN;
  const int q    = lane >> 4, l16 = lane & 15;

  // staging coords
  const int ar  = tid >> 1;              // A: 2 threads/row, 16 k each
  const int akq = (tid & 1) * 16;
  const int wr  = (BN == 128) ? (tid >> 1) : (tid >> 2);
  const int wkq = (BN == 128) ? ((tid & 1) * 16) : ((tid & 3) * 8);
  const int wrow = n0 + wr;
  const bool wv  = (wrow < N);

  const float*    Af = (const float*)Av;
  const _Float16* Ah = (const _Float16*)Av;
  const float*    Wp = W + (size_t)wrow * K;
  const size_t aoff = (size_t)(m0 + ar) * lda + akq;   // m0 included (R7 fix)

  float4 raf[4]; half8 rah[2]; float4 rwf[4];
  const float4 zf4 = make_float4(0.f, 0.f, 0.f, 0.f);

  // initial loads (k0 = 0)
  if (AF16) {
    const _Float16* p = Ah + aoff;
    rah[0] = *(const half8*)p; rah[1] = *(const half8*)(p + 8);
  } else {
    const float* p = Af + aoff;
    raf[0] = *(const float4*)p;       raf[1] = *(const float4*)(p + 4);
    raf[2] = *(const float4*)(p + 8); raf[3] = *(const float4*)(p + 12);
  }
  if (BN == 128) {
    if (wv) {
      const float* p = Wp + wkq;
      rwf[0] = *(const float4*)p;       rwf[1] = *(const float4*)(p + 4);
      rwf[2] = *(const float4*)(p + 8); rwf[3] = *(const float4*)(p + 12);
    } else { rwf[0] = rwf[1] = rwf[2] = rwf[3] = zf4; }
  } else {
    if (wv) {
      const float* p = Wp + wkq;
      rwf[0] = *(const float4*)p; rwf[1] = *(const float4*)(p + 4);
    } else { rwf[0] = rwf[1] = zf4; }
  }

  f32x4 acc[4][NF];
  #pragma unroll
  for (int mi = 0; mi < 4; ++mi)
    #pragma unroll
    for (int ni = 0; ni < NF; ++ni)
      acc[mi][ni] = (f32x4){0.f, 0.f, 0.f, 0.f};

  for (int k0 = 0; k0 < K; k0 += 32) {
    if (k0) __syncthreads();
    if (AF16) {
      *(half8*)&As[ar * 40 + akq]     = rah[0];
      *(half8*)&As[ar * 40 + akq + 8] = rah[1];
    } else {
      *(half8*)&As[ar * 40 + akq]     = pack_f16(raf[0], raf[1]);
      *(half8*)&As[ar * 40 + akq + 8] = pack_f16(raf[2], raf[3]);
    }
    if (BN == 128) {
      *(half8*)&Ws[wr * 40 + wkq]     = pack_f16(rwf[0], rwf[1]);
      *(half8*)&Ws[wr * 40 + wkq + 8] = pack_f16(rwf[2], rwf[3]);
    } else {
      *(half8*)&Ws[wr * 40 + wkq]     = pack_f16(rwf[0], rwf[1]);
    }
    __syncthreads();

    if (k0 + 32 < K) {            // prefetch next chunk (in flight over MFMAs)
      const int kn = k0 + 32;
      if (AF16) {
        const _Float16* p = Ah + aoff + kn;
        rah[0] = *(const half8*)p; rah[1] = *(const half8*)(p + 8);
      } else {
        const float* p = Af + aoff + kn;
        raf[0] = *(const float4*)p;       raf[1] = *(const float4*)(p + 4);
        raf[2] = *(const float4*)(p + 8); raf[3] = *(const float4*)(p + 12);
      }
      if (BN == 128) {
        if (wv) {
          const float* p = Wp + kn + wkq;
          rwf[0] = *(const float4*)p;       rwf[1] = *(const float4*)(p + 4);
          rwf[2] = *(const float4*)(p + 8); rwf[3] = *(const float4*)(p + 12);
        }
      } else {
        if (wv) {
          const float* p = Wp + kn + wkq;
          rwf[0] = *(const float4*)p; rwf[1] = *(const float4*)(p + 4);
        }
      }
    }

    half8 af[4], wf[NF];
    #pragma unroll
    for (int mi = 0; mi < 4; ++mi)
      af[mi] = *(const half8*)&As[(wm * 64 + mi * 16 + l16) * 40 + q * 8];
    #pragma unroll
    for (int ni = 0; ni < NF; ++ni)
      wf[ni] = *(const half8*)&Ws[(wn * (BN / 2) + ni * 16 + l16) * 40 + q * 8];
    #pragma unroll
    for (int mi = 0; mi < 4; ++mi)
      #pragma unroll
      for (int ni = 0; ni < NF; ++ni)
        acc[mi][ni] = __builtin_amdgcn_mfma_f32_16x16x32_f16(af[mi], wf[ni],
                                                             acc[mi][ni], 0, 0, 0);
  }

  float*    Cf = (float*)Cv;
  _Float16* Ch = (_Float16*)Cv;

  if (MODE == 1) {
    // fused in_proj epilogue: branch is block-uniform (BN=128 divides 1024)
    _Float16* Ch2 = (_Float16*)Cv2;
    #pragma unroll
    for (int ni = 0; ni < NF; ++ni) {
      const int n = n0 + wn * (BN / 2) + ni * 16 + l16;
      if (n < 1024) {
        #pragma unroll
        for (int mi = 0; mi < 4; ++mi) {
          const int mb = m0 + wm * 64 + mi * 16 + q * 4;
          #pragma unroll
          for (int r = 0; r < 4; ++r)
            Cf[(size_t)(mb + r) * 1024 + n] = acc[mi][ni][r];
        }
      } else {
        const int nn = n - 1024;
        #pragma unroll
        for (int mi = 0; mi < 4; ++mi) {
          const int mb = m0 + wm * 64 + mi * 16 + q * 4;
          half4v h4;
          #pragma unroll
          for (int r = 0; r < 4; ++r) h4[r] = (_Float16)silu_f(acc[mi][ni][r]);
          *(half4v*)&Ch2[(size_t)nn * 4096 + mb] = h4;
        }
      }
    }
    return;
  }

  // MODE 0 epilogue
  #pragma unroll
  for (int ni = 0; ni < NF; ++ni) {
    const int n = n0 + wn * (BN / 2) + ni * 16 + l16;
    if (n < N) {
      const float bv = (bias != nullptr) ? bias[n] : 0.f;
      #pragma unroll
      for (int mi = 0; mi < 4; ++mi) {
        const int mb = m0 + wm * 64 + mi * 16 + q * 4;
        float o[4];
        #pragma unroll
        for (int r = 0; r < 4; ++r) {
          float v = acc[mi][ni][r] * oscale + bv;
          if (ACT == 1) v = (v > 20.f) ? v : log1pf(__expf(v));
          if (ACT == 2) v = silu_f(v);
          o[r] = v;
        }
        if (TC == 0) {
          #pragma unroll
          for (int r = 0; r < 4; ++r) {
            size_t off = (size_t)(mb + r) * ldc + n;
            if (OF16) Ch[off] = (_Float16)o[r];
            else      Cf[off] = o[r];
          }
        } else {
          size_t off = (size_t)n * ldc + mb;
          if (OF16) {
            half4v h4; h4[0]=(_Float16)o[0]; h4[1]=(_Float16)o[1];
                       h4[2]=(_Float16)o[2]; h4[3]=(_Float16)o[3];
            *(half4v*)&Ch[off] = h4;
          } else {
            *(float4*)&Cf[off] = make_float4(o[0], o[1], o[2], o[3]);
          }
        }
      }
    }
  }
}

// ---------------------------------------------------------------------------
// Depthwise causal conv (D_CONV=2) + silu, 64x64 LDS transpose.
// in : xcp [4096 bl][1024 d] fp32
// out: xcT [1024 d][4096 bl] fp32 (scan input)  +  xcf [4096 bl][1024 d] f16
// ---------------------------------------------------------------------------
__global__ void conv_t_kernel(const float* __restrict__ xcp,
                              const float* __restrict__ cw,   // [1024][2]
                              const float* __restrict__ cb,   // [1024]
                              float* __restrict__ xcT,
                              _Float16* __restrict__ xcf)
{
  __shared__ float tile[64][65];
  const int blk = blockIdx.x;            // b*256 + tt*16 + dd
  const int b  = blk >> 8;
  const int tt = (blk >> 4) & 15;
  const int dd = blk & 15;
  const int t0 = tt * 64, d0 = dd * 64;
  const int tid = threadIdx.x;

  #pragma unroll
  for (int i = 0; i < 16; ++i) {
    int idx = i * 256 + tid;
    int t = idx >> 6, d = idx & 63;
    int gt = t0 + t;
    size_t rcur = ((size_t)(b * 1024 + gt) << 10) + d0 + d;
    float cur  = xcp[rcur];
    float prev = (gt > 0) ? xcp[rcur - 1024] : 0.f;
    float v = fmaf(prev, cw[(d0+d)*2], fmaf(cur, cw[(d0+d)*2 + 1], cb[d0+d]));
    float sv = silu_f(v);
    tile[t][d] = sv;
    xcf[rcur] = (_Float16)sv;
  }
  __syncthreads();
  #pragma unroll
  for (int i = 0; i < 16; ++i) {
    int idx = i * 256 + tid;
    int d = idx >> 6, t = idx & 63;
    xcT[((size_t)(d0 + d) << 12) + b * 1024 + t0 + t] = tile[t][d];
  }
}

// ---------------------------------------------------------------------------
// Transpose + f16 convert WITH 2^14 scaling:
// src [1024 d][4096 bl] fp32 -> dst [4096 bl][1024 d] f16, dst = src * 16384.
// ---------------------------------------------------------------------------
__global__ void trans_f16_kernel(const float* __restrict__ src,
                                 _Float16* __restrict__ dst)
{
  __shared__ float tile[64][65];
  const int bl0 = blockIdx.x * 64;
  const int d0  = blockIdx.y * 64;
  const int tid = threadIdx.x;
  #pragma unroll
  for (int i = 0; i < 16; ++i) {
    int idx = i * 256 + tid;
    int r = idx >> 6, c = idx & 63;     // r: d, c: bl
    tile[r][c] = src[((size_t)(d0 + r) << 12) + bl0 + c];
  }
  __syncthreads();
  #pragma unroll
  for (int i = 0; i < 16; ++i) {
    int idx = i * 256 + tid;
    int c = idx >> 6, r = idx & 63;     // write rows bl, cols d
    dst[((size_t)(bl0 + c) << 10) + d0 + r] = (_Float16)(tile[r][c] * Y_SCALE);
  }
}

// ---------------------------------------------------------------------------
// Selective scan, time-major. One wave per (b,d), lane = s (D_STATE=64).
// R9: (a) exp restored to __expf fast path (R8's exp2f builtin lowered to
// precise libm code — regression). (b) B/C cooperatively staged to LDS,
// double-buffered: the 4 waves of a block share b, so dbc rows are loaded
// once per block instead of 4x, via coalesced float4; next chunk's loads
// issue before compute so VMEM latency overlaps. (c) all h-independent math
// (dA, u*B) hoisted to a parallel phase; serial loop = fma+mul+ds_write.
// y = (scan + x*Dp) * silu(z) written IN PLACE over xcT.
// ---------------------------------------------------------------------------
__global__ __launch_bounds__(256, 4)
void scan_kernel(const float* __restrict__ dtT,     // [1024][4096]
                 float* __restrict__ xcT,           // [1024][4096]; y in place
                 const _Float16* __restrict__ zsT,  // [1024][4096], silu(z), f16
                 const float* __restrict__ dbc,     // [B][1024][160]; B@+32, C@+96
                 const float* __restrict__ A_log,   // [1024][64]
                 const float* __restrict__ Dp)      // [1024]
{
  __shared__ float P[4][16][68];       // per-wave reduction tile
  __shared__ float BC[2][2][16][64];   // [buf][B/C][t][s], block-shared
  const int tid  = threadIdx.x;
  const int lane = tid & 63;
  const int wrp  = tid >> 6;
  const int wid  = __builtin_amdgcn_readfirstlane(blockIdx.x * 4 + wrp);
  const int b = wid >> 10;             // block-uniform (blocks never straddle b)
  const int d = wid & 1023;
  float (*Pw)[68] = P[wrp];

  const float a   = -__expf(A_log[d*64 + lane]);
  const float dpv = Dp[d];
  const size_t row = ((size_t)d << 12) + b * 1024;
  const float*    dtp = dtT + row;
  float*          xyp = xcT + row;
  const _Float16* zsp = zsT + row;

  // cooperative B/C staging coords: thread -> (t in chunk, s-quad)
  const int ct = tid >> 4;             // 0..15
  const int cs = (tid & 15) * 4;       // 0..60
  const float* bcbase = dbc + (size_t)b * 163840 + (size_t)ct * 160 + cs;

  const int tt_r = lane >> 2;          // which timestep this lane reduces
  const int c0   = (lane & 3) << 4;    // which 16-state chunk

  // preload chunk 0 into buf 0
  {
    float4 b0 = *(const float4*)(bcbase + 32);
    float4 c0q = *(const float4*)(bcbase + 96);
    *(float4*)&BC[0][0][ct][cs] = b0;
    *(float4*)&BC[0][1][ct][cs] = c0q;
  }
  __syncthreads();

  float h = 0.f;
  for (int t0 = 0; t0 < 1024; t0 += 16) {
    const int p = (t0 >> 4) & 1;
    // ---- issue next chunk's global loads first (latency overlaps compute) --
    const int tn = (t0 + 16 < 1024) ? (t0 + 16) : t0;
    float4 nb = *(const float4*)(bcbase + (size_t)tn * 160 + 32);
    float4 nc = *(const float4*)(bcbase + (size_t)tn * 160 + 96);

    // ---- per-wave loads for current chunk ----
    float4 dq[4], xq[4];
    #pragma unroll
    for (int i = 0; i < 4; ++i) {
      dq[i] = *(const float4*)(dtp + t0 + i*4);
      xq[i] = *(const float4*)(xyp + t0 + i*4);
    }
    float zs  = (float)zsp[t0 + tt_r];
    float xvl = xyp[t0 + tt_r];          // this lane's x (read before y store)
    const float* dtv = reinterpret_cast<const float*>(dq);
    const float* xv  = reinterpret_cast<const float*>(xq);

    // ---- parallel phase: everything h-independent ----
    float dA[16], ub[16], Cv[16];
    #pragma unroll
    for (int tt = 0; tt < 16; ++tt) {
      float Bv = BC[p][0][tt][lane];
      Cv[tt]   = BC[p][1][tt][lane];
      dA[tt] = __expf(dtv[tt] * a);
      ub[tt] = dtv[tt] * xv[tt] * Bv;
    }
    // ---- serial recurrence: fma -> mul -> ds_write per t ----
    #pragma unroll
    for (int tt = 0; tt < 16; ++tt) {
      h = fmaf(h, dA[tt], ub[tt]);
      Pw[tt][lane] = h * Cv[tt];
    }

    // ---- batched reduction: lane L sums 16 states of timestep L>>2 ----
    float4 s0 = *(const float4*)&Pw[tt_r][c0];
    float4 s1 = *(const float4*)&Pw[tt_r][c0 + 4];
    float4 s2 = *(const float4*)&Pw[tt_r][c0 + 8];
    float4 s3 = *(const float4*)&Pw[tt_r][c0 + 12];
    float r = ((s0.x + s0.y) + (s0.z + s0.w))
            + ((s1.x + s1.y) + (s1.z + s1.w))
            + ((s2.x + s2.y) + (s2.z + s2.w))
            + ((s3.x + s3.y) + (s3.z + s3.w));
    r += __shfl_xor(r, 1, 64);
    r += __shfl_xor(r, 2, 64);
    if ((lane & 3) == 0)
      xyp[t0 + tt_r] = fmaf(xvl, dpv, r) * zs;

    // ---- stage next chunk into the other buffer, then sync ----
    *(float4*)&BC[1 - p][0][ct][cs] = nb;
    *(float4*)&BC[1 - p][1][ct][cs] = nc;
    __syncthreads();
  }
}

// out[b,c] = h[b,L-1,:] . fc_w[c,:] + fc_b[c]; h is fp32 [4096][512]
__global__ void head_kernel(const float* __restrict__ h,
                            const float* __restrict__ fc_w,
                            const float* __restrict__ fc_b,
                            float* __restrict__ out)
{
  int bc = blockIdx.x;            // 0..11
  int b = bc / 3, c = bc % 3;
  int lane = threadIdx.x;
  const float* hr = h + (size_t)(b*1024 + 1023) * 512;
  const float* wr = fc_w + c*512;
  float s = 0.f;
  #pragma unroll
  for (int i = 0; i < 8; ++i) s = fmaf(hr[lane + i*64], wr[lane + i*64], s);
  #pragma unroll
  for (int o = 32; o > 0; o >>= 1) s += __shfl_xor(s, o, 64);
  if (lane == 0) out[b*3 + c] = s + fc_b[c];
}

extern "C" void kernel_launch(void* const* d_in, const int* in_sizes, int n_in,
                              void* d_out, int out_size, void* d_ws, size_t ws_size,
                              hipStream_t stream)
{
  const float* x        = (const float*)d_in[0];
  const float* exp_w    = (const float*)d_in[1];
  const float* exp_b    = (const float*)d_in[2];
  const float* in_w     = (const float*)d_in[3];
  const float* conv_w   = (const float*)d_in[4];
  const float* conv_b   = (const float*)d_in[5];
  const float* xproj_w  = (const float*)d_in[6];
  const float* dtproj_w = (const float*)d_in[7];
  const float* dtproj_b = (const float*)d_in[8];
  const float* A_log    = (const float*)d_in[9];
  const float* Dp       = (const float*)d_in[10];
  const float* out_w    = (const float*)d_in[11];
  const float* fc_w     = (const float*)d_in[12];
  const float* fc_b     = (const float*)d_in[13];
  float* out = (float*)d_out;

  // Workspace layout (byte offsets), 59 MB total. The 8..24 MB region is
  // sequentially reused: xcpre (in_proj -> conv_t) -> dtT (dtproj -> scan)
  // -> y16 (trans_f16 -> out_proj).
  char* ws = (char*)d_ws;
  float*    hf    = (float*)   (ws);                          //  8 MB [4096][512] fp32
  float*    xcpre = (float*)   (ws + ((size_t)8  << 20));     // 16 MB [4096][1024]
  float*    dtT   = (float*)   (ws + ((size_t)8  << 20));     // 16 MB [1024][4096] (reuse)
  _Float16* y16   = (_Float16*)(ws + ((size_t)8  << 20));     //  8 MB [4096][1024] (reuse)
  float*    xcT   = (float*)   (ws + ((size_t)24 << 20));     // 16 MB [1024][4096]
  _Float16* zsT   = (_Float16*)(ws + ((size_t)40 << 20));     //  8 MB [1024][4096]
  float*    dbc   = (float*)   (ws + ((size_t)48 << 20));     //  2.6 MB [4096][160]
  _Float16* xc16  = (_Float16*)(ws + ((size_t)51 << 20));     //  8 MB [4096][1024]

  dim3 blk(256);

  // expand: hf = x @ exp_w^T + exp_b   [4096,512] K=128, fp32 out
  gemm_mfma<0,128,0,0,0,0><<<dim3(4,32), blk, 0, stream>>>(x, 128, exp_w, exp_b,
                                                           hf, 512, 512, 128, 1.f, nullptr);

  for (int l = 0; l < 2; ++l) {
    const float* inw = in_w + (size_t)l * 2048 * 512;
    // fused in_proj: xcpre [4096][1024] f32 + zsT [1024][4096] silu f16, N=2048 K=512
    gemm_mfma<0,128,0,0,0,1><<<dim3(16,32), blk, 0, stream>>>(hf, 512, inw, nullptr,
                                                              xcpre, 1024, 2048, 512, 1.f,
                                                              zsT);
    // conv + silu -> xcT (fp32, scan) + xc16 (f16, xproj A)
    conv_t_kernel<<<1024, blk, 0, stream>>>(xcpre, conv_w + l*2048, conv_b + l*1024,
                                            xcT, xc16);
    // xproj: dbc = xc @ xproj_w^T   [4096,160] K=1024
    gemm_mfma<1,64,0,0,0,0><<<dim3(3,32), blk, 0, stream>>>(xc16, 1024,
                                                            xproj_w + (size_t)l*160*1024,
                                                            nullptr, dbc, 160, 160, 1024,
                                                            1.f, nullptr);
    // dtproj (transposed + softplus): dtT [1024][4096], K=32 (overwrites xcpre — dead)
    gemm_mfma<0,128,1,1,0,0><<<dim3(8,32), blk, 0, stream>>>(dbc, 160,
                                                             dtproj_w + (size_t)l*1024*32,
                                                             dtproj_b + l*1024,
                                                             dtT, 4096, 1024, 32, 1.f,
                                                             nullptr);
    // selective scan; y = (scan + x*Dp)*silu(z) over xcT
    scan_kernel<<<1024, blk, 0, stream>>>(dtT, xcT, zsT, dbc,
                                          A_log + (size_t)l*65536, Dp + l*1024);
    // y -> y16 = f16(y * 2^14) [4096][1024]   (overwrites dtT — dead)
    trans_f16_kernel<<<dim3(64,16), blk, 0, stream>>>(xcT, y16);
    // out_proj: hf = (y16 @ out_w^T) * 2^-14   [4096,512] K=1024, fp32 out
    gemm_mfma<1,64,0,0,0,0><<<dim3(8,32), blk, 0, stream>>>(y16, 1024,
                                                            out_w + (size_t)l*512*1024,
                                                            nullptr, hf, 512, 512, 1024,
                                                            1.f / Y_SCALE, nullptr);
  }

  head_kernel<<<12, 64, 0, stream>>>(hf, fc_w, fc_b, out);
}

// Round 10
// 508.310 us; speedup vs baseline: 3.5208x; 1.0502x over previous
//
#include <hip/hip_runtime.h>
#include <math.h>

// Problem constants: B=4, L=1024, D_IN=128, D_MODEL=512, N_LAYERS=2,
// N_CLASSES=3, D_INNER=1024, D_STATE=64, D_CONV=2, DT_RANK=32, BL=4096.
//
// Precision plan (values shrink ~1000x per layer; final output ~3e-8):
//  - residual h kept fp32 end-to-end (layer-2 h ~3e-8 is f16-subnormal).
//  - y (out_proj A operand) scaled by 2^14 before f16 conversion; out_proj
//    epilogue multiplies by 2^-14 (exact powers of two).

using half8  = __attribute__((ext_vector_type(8))) _Float16;
using half4v = __attribute__((ext_vector_type(4))) _Float16;
using f32x4  = __attribute__((ext_vector_type(4))) float;

#define Y_SCALE 16384.0f   // 2^14

__device__ __forceinline__ float silu_f(float v) {
  return v / (1.f + __expf(-v));
}

__device__ __forceinline__ half8 pack_f16(float4 a, float4 b) {
  half8 r;
  r[0] = (_Float16)a.x; r[1] = (_Float16)a.y; r[2] = (_Float16)a.z; r[3] = (_Float16)a.w;
  r[4] = (_Float16)b.x; r[5] = (_Float16)b.y; r[6] = (_Float16)b.z; r[7] = (_Float16)b.w;
  return r;
}

// ---------------------------------------------------------------------------
// f16 MFMA GEMM, 64 x BN tile (R10: BM 128->64 for 2-4x more blocks/CU —
// out_proj was 1 block/CU at BM=128). Block 256 thr = 4 waves; wave-tile
// 32 x (BN/2), MI=2 m-frags. BK=32 (one mfma_16x16x32 k-step).
// A: [M][K] row-major, fp32 (AF16=0) or f16 (AF16=1), leading dim lda.
// W: [N][K] fp32 row-major (converted to f16 in staging).
// MODE 0: C per TC/ACT/OF16 (TC=0 -> [M][N]; TC=1 -> [N][M]).
// MODE 1 (fused in_proj, N=2048): n<1024 -> Cv fp32 [M][1024];
//        n>=1024 -> Cv2 f16 silu transposed [n-1024][4096].
// MFMA layouts (m89/m120-verified): A-frag A[m=lane&15][k=q*8+j],
// B-frag B[k=q*8+j][n=lane&15], D: col(n)=lane&15, row(m)=q*4+r.
// ---------------------------------------------------------------------------
template<int AF16, int BN, int TC, int ACT, int OF16, int MODE>
__global__ __launch_bounds__(256)
void gemm_mfma(const void* __restrict__ Av, int lda,
               const float* __restrict__ W,
               const float* __restrict__ bias,
               void* __restrict__ Cv, int ldc,
               int N, int K, float oscale,
               void* __restrict__ Cv2)
{
  constexpr int NF = BN / 32;            // n-frags per wave
  __shared__ _Float16 As[64 * 40];       // [m][k], row stride 40 f16 (80 B)
  __shared__ _Float16 Ws[BN * 40];       // [n][k]
  const int tid  = threadIdx.x;
  const int lane = tid & 63;
  const int wid  = tid >> 6;
  const int wm   = wid & 1, wn = wid >> 1;   // wave-tile: 32 m x BN/2 n
  const int m0   = blockIdx.y * 64;
  const int n0   = blockIdx.x * BN;
  const int q    = lane >> 4, l16 = lane & 15;

  // A staging: 64 rows, 4 threads/row, 8 halfs each
  const int ar  = tid >> 2;
  const int akq = (tid & 3) * 8;
  // W staging: BN=128: 2 thr/row x 16 halfs; BN=64: 4 thr/row x 8 halfs
  const int wr  = (BN == 128) ? (tid >> 1) : (tid >> 2);
  const int wkq = (BN == 128) ? ((tid & 1) * 16) : ((tid & 3) * 8);
  const int wrow = n0 + wr;
  const bool wv  = (wrow < N);

  const float*    Af = (const float*)Av;
  const _Float16* Ah = (const _Float16*)Av;
  const float*    Wp = W + (size_t)wrow * K;
  const size_t aoff = (size_t)(m0 + ar) * lda + akq;

  float4 raf[2]; half8 rah; float4 rwf[4];
  const float4 zf4 = make_float4(0.f, 0.f, 0.f, 0.f);

  // initial loads (k0 = 0)
  if (AF16) {
    rah = *(const half8*)(Ah + aoff);
  } else {
    const float* p = Af + aoff;
    raf[0] = *(const float4*)p; raf[1] = *(const float4*)(p + 4);
  }
  if (BN == 128) {
    if (wv) {
      const float* p = Wp + wkq;
      rwf[0] = *(const float4*)p;       rwf[1] = *(const float4*)(p + 4);
      rwf[2] = *(const float4*)(p + 8); rwf[3] = *(const float4*)(p + 12);
    } else { rwf[0] = rwf[1] = rwf[2] = rwf[3] = zf4; }
  } else {
    if (wv) {
      const float* p = Wp + wkq;
      rwf[0] = *(const float4*)p; rwf[1] = *(const float4*)(p + 4);
    } else { rwf[0] = rwf[1] = zf4; }
  }

  f32x4 acc[2][NF];
  #pragma unroll
  for (int mi = 0; mi < 2; ++mi)
    #pragma unroll
    for (int ni = 0; ni < NF; ++ni)
      acc[mi][ni] = (f32x4){0.f, 0.f, 0.f, 0.f};

  for (int k0 = 0; k0 < K; k0 += 32) {
    if (k0) __syncthreads();
    if (AF16) *(half8*)&As[ar * 40 + akq] = rah;
    else      *(half8*)&As[ar * 40 + akq] = pack_f16(raf[0], raf[1]);
    if (BN == 128) {
      *(half8*)&Ws[wr * 40 + wkq]     = pack_f16(rwf[0], rwf[1]);
      *(half8*)&Ws[wr * 40 + wkq + 8] = pack_f16(rwf[2], rwf[3]);
    } else {
      *(half8*)&Ws[wr * 40 + wkq]     = pack_f16(rwf[0], rwf[1]);
    }
    __syncthreads();

    if (k0 + 32 < K) {            // prefetch next chunk
      const int kn = k0 + 32;
      if (AF16) {
        rah = *(const half8*)(Ah + aoff + kn);
      } else {
        const float* p = Af + aoff + kn;
        raf[0] = *(const float4*)p; raf[1] = *(const float4*)(p + 4);
      }
      if (BN == 128) {
        if (wv) {
          const float* p = Wp + kn + wkq;
          rwf[0] = *(const float4*)p;       rwf[1] = *(const float4*)(p + 4);
          rwf[2] = *(const float4*)(p + 8); rwf[3] = *(const float4*)(p + 12);
        }
      } else {
        if (wv) {
          const float* p = Wp + kn + wkq;
          rwf[0] = *(const float4*)p; rwf[1] = *(const float4*)(p + 4);
        }
      }
    }

    half8 af[2], wf[NF];
    #pragma unroll
    for (int mi = 0; mi < 2; ++mi)
      af[mi] = *(const half8*)&As[(wm * 32 + mi * 16 + l16) * 40 + q * 8];
    #pragma unroll
    for (int ni = 0; ni < NF; ++ni)
      wf[ni] = *(const half8*)&Ws[(wn * (BN / 2) + ni * 16 + l16) * 40 + q * 8];
    #pragma unroll
    for (int mi = 0; mi < 2; ++mi)
      #pragma unroll
      for (int ni = 0; ni < NF; ++ni)
        acc[mi][ni] = __builtin_amdgcn_mfma_f32_16x16x32_f16(af[mi], wf[ni],
                                                             acc[mi][ni], 0, 0, 0);
  }

  float*    Cf = (float*)Cv;
  _Float16* Ch = (_Float16*)Cv;

  if (MODE == 1) {
    // fused in_proj epilogue: branch is block-uniform (BN=128 divides 1024)
    _Float16* Ch2 = (_Float16*)Cv2;
    #pragma unroll
    for (int ni = 0; ni < NF; ++ni) {
      const int n = n0 + wn * (BN / 2) + ni * 16 + l16;
      if (n < 1024) {
        #pragma unroll
        for (int mi = 0; mi < 2; ++mi) {
          const int mb = m0 + wm * 32 + mi * 16 + q * 4;
          #pragma unroll
          for (int r = 0; r < 4; ++r)
            Cf[(size_t)(mb + r) * 1024 + n] = acc[mi][ni][r];
        }
      } else {
        const int nn = n - 1024;
        #pragma unroll
        for (int mi = 0; mi < 2; ++mi) {
          const int mb = m0 + wm * 32 + mi * 16 + q * 4;
          half4v h4;
          #pragma unroll
          for (int r = 0; r < 4; ++r) h4[r] = (_Float16)silu_f(acc[mi][ni][r]);
          *(half4v*)&Ch2[(size_t)nn * 4096 + mb] = h4;
        }
      }
    }
    return;
  }

  // MODE 0 epilogue
  #pragma unroll
  for (int ni = 0; ni < NF; ++ni) {
    const int n = n0 + wn * (BN / 2) + ni * 16 + l16;
    if (n < N) {
      const float bv = (bias != nullptr) ? bias[n] : 0.f;
      #pragma unroll
      for (int mi = 0; mi < 2; ++mi) {
        const int mb = m0 + wm * 32 + mi * 16 + q * 4;
        float o[4];
        #pragma unroll
        for (int r = 0; r < 4; ++r) {
          float v = acc[mi][ni][r] * oscale + bv;
          if (ACT == 1) v = (v > 20.f) ? v : log1pf(__expf(v));
          if (ACT == 2) v = silu_f(v);
          o[r] = v;
        }
        if (TC == 0) {
          #pragma unroll
          for (int r = 0; r < 4; ++r) {
            size_t off = (size_t)(mb + r) * ldc + n;
            if (OF16) Ch[off] = (_Float16)o[r];
            else      Cf[off] = o[r];
          }
        } else {
          size_t off = (size_t)n * ldc + mb;
          if (OF16) {
            half4v h4; h4[0]=(_Float16)o[0]; h4[1]=(_Float16)o[1];
                       h4[2]=(_Float16)o[2]; h4[3]=(_Float16)o[3];
            *(half4v*)&Ch[off] = h4;
          } else {
            *(float4*)&Cf[off] = make_float4(o[0], o[1], o[2], o[3]);
          }
        }
      }
    }
  }
}

// ---------------------------------------------------------------------------
// Depthwise causal conv (D_CONV=2) + silu, 64x64 LDS transpose.
// in : xcp [4096 bl][1024 d] fp32
// out: xcT [1024 d][4096 bl] fp32 (scan input)  +  xcf [4096 bl][1024 d] f16
// ---------------------------------------------------------------------------
__global__ void conv_t_kernel(const float* __restrict__ xcp,
                              const float* __restrict__ cw,   // [1024][2]
                              const float* __restrict__ cb,   // [1024]
                              float* __restrict__ xcT,
                              _Float16* __restrict__ xcf)
{
  __shared__ float tile[64][65];
  const int blk = blockIdx.x;            // b*256 + tt*16 + dd
  const int b  = blk >> 8;
  const int tt = (blk >> 4) & 15;
  const int dd = blk & 15;
  const int t0 = tt * 64, d0 = dd * 64;
  const int tid = threadIdx.x;

  #pragma unroll
  for (int i = 0; i < 16; ++i) {
    int idx = i * 256 + tid;
    int t = idx >> 6, d = idx & 63;
    int gt = t0 + t;
    size_t rcur = ((size_t)(b * 1024 + gt) << 10) + d0 + d;
    float cur  = xcp[rcur];
    float prev = (gt > 0) ? xcp[rcur - 1024] : 0.f;
    float v = fmaf(prev, cw[(d0+d)*2], fmaf(cur, cw[(d0+d)*2 + 1], cb[d0+d]));
    float sv = silu_f(v);
    tile[t][d] = sv;
    xcf[rcur] = (_Float16)sv;
  }
  __syncthreads();
  #pragma unroll
  for (int i = 0; i < 16; ++i) {
    int idx = i * 256 + tid;
    int d = idx >> 6, t = idx & 63;
    xcT[((size_t)(d0 + d) << 12) + b * 1024 + t0 + t] = tile[t][d];
  }
}

// ---------------------------------------------------------------------------
// Transpose + f16 convert WITH 2^14 scaling:
// src [1024 d][4096 bl] fp32 -> dst [4096 bl][1024 d] f16, dst = src * 16384.
// ---------------------------------------------------------------------------
__global__ void trans_f16_kernel(const float* __restrict__ src,
                                 _Float16* __restrict__ dst)
{
  __shared__ float tile[64][65];
  const int bl0 = blockIdx.x * 64;
  const int d0  = blockIdx.y * 64;
  const int tid = threadIdx.x;
  #pragma unroll
  for (int i = 0; i < 16; ++i) {
    int idx = i * 256 + tid;
    int r = idx >> 6, c = idx & 63;     // r: d, c: bl
    tile[r][c] = src[((size_t)(d0 + r) << 12) + bl0 + c];
  }
  __syncthreads();
  #pragma unroll
  for (int i = 0; i < 16; ++i) {
    int idx = i * 256 + tid;
    int c = idx >> 6, r = idx & 63;     // write rows bl, cols d
    dst[((size_t)(bl0 + c) << 10) + d0 + r] = (_Float16)(tile[r][c] * Y_SCALE);
  }
}

// ---------------------------------------------------------------------------
// Selective scan, time-major. One wave per (b,d), lane = s (D_STATE=64).
// R9: B/C block-shared in LDS (double-buffered; 4 waves share b).
// R10: dt/x/zs/xvl ALSO register-prefetched one chunk ahead — removes the
// chunk-start SMEM/VMEM latency stall (scan was latency-bound: VALUBusy 57%
// at fixed 16 waves/CU). Last-iter clamped prefetch reads pre-store
// addresses only into discarded registers.
// y = (scan + x*Dp) * silu(z) written IN PLACE over xcT.
// ---------------------------------------------------------------------------
__global__ __launch_bounds__(256, 4)
void scan_kernel(const float* __restrict__ dtT,     // [1024][4096]
                 float* __restrict__ xcT,           // [1024][4096]; y in place
                 const _Float16* __restrict__ zsT,  // [1024][4096], silu(z), f16
                 const float* __restrict__ dbc,     // [B][1024][160]; B@+32, C@+96
                 const float* __restrict__ A_log,   // [1024][64]
                 const float* __restrict__ Dp)      // [1024]
{
  __shared__ float P[4][16][68];       // per-wave reduction tile
  __shared__ float BC[2][2][16][64];   // [buf][B/C][t][s], block-shared
  const int tid  = threadIdx.x;
  const int lane = tid & 63;
  const int wrp  = tid >> 6;
  const int wid  = __builtin_amdgcn_readfirstlane(blockIdx.x * 4 + wrp);
  const int b = wid >> 10;             // block-uniform (blocks never straddle b)
  const int d = wid & 1023;
  float (*Pw)[68] = P[wrp];

  const float a   = -__expf(A_log[d*64 + lane]);
  const float dpv = Dp[d];
  const size_t row = ((size_t)d << 12) + b * 1024;
  const float*    dtp = dtT + row;
  float*          xyp = xcT + row;
  const _Float16* zsp = zsT + row;

  // cooperative B/C staging coords: thread -> (t in chunk, s-quad)
  const int ct = tid >> 4;             // 0..15
  const int cs = (tid & 15) * 4;       // 0..60
  const float* bcbase = dbc + (size_t)b * 163840 + (size_t)ct * 160 + cs;

  const int tt_r = lane >> 2;          // which timestep this lane reduces
  const int c0   = (lane & 3) << 4;    // which 16-state chunk

  // ---- preload chunk 0: BC buf0 + per-wave dt/x/zs/xvl ----
  float4 dq[4], xq[4];
  float zs, xvl;
  {
    *(float4*)&BC[0][0][ct][cs] = *(const float4*)(bcbase + 32);
    *(float4*)&BC[0][1][ct][cs] = *(const float4*)(bcbase + 96);
    #pragma unroll
    for (int i = 0; i < 4; ++i) {
      dq[i] = *(const float4*)(dtp + i*4);
      xq[i] = *(const float4*)(xyp + i*4);
    }
    zs  = (float)zsp[tt_r];
    xvl = xyp[tt_r];
  }
  __syncthreads();

  float h = 0.f;
  for (int t0 = 0; t0 < 1024; t0 += 16) {
    const int p = (t0 >> 4) & 1;
    const int tn = (t0 + 16 < 1024) ? (t0 + 16) : t0;   // clamped prefetch

    // ---- issue ALL of next chunk's loads first (latency overlaps compute) --
    float4 nb = *(const float4*)(bcbase + (size_t)tn * 160 + 32);
    float4 nc = *(const float4*)(bcbase + (size_t)tn * 160 + 96);
    float4 nd[4], nx[4];
    #pragma unroll
    for (int i = 0; i < 4; ++i) {
      nd[i] = *(const float4*)(dtp + tn + i*4);
      nx[i] = *(const float4*)(xyp + tn + i*4);
    }
    float nzs  = (float)zsp[tn + tt_r];
    float nxvl = xyp[tn + tt_r];

    const float* dtv = reinterpret_cast<const float*>(dq);
    const float* xv  = reinterpret_cast<const float*>(xq);

    // ---- parallel phase: everything h-independent ----
    float dA[16], ub[16], Cv[16];
    #pragma unroll
    for (int tt = 0; tt < 16; ++tt) {
      float Bv = BC[p][0][tt][lane];
      Cv[tt]   = BC[p][1][tt][lane];
      dA[tt] = __expf(dtv[tt] * a);
      ub[tt] = dtv[tt] * xv[tt] * Bv;
    }
    // ---- serial recurrence: fma -> mul -> ds_write per t ----
    #pragma unroll
    for (int tt = 0; tt < 16; ++tt) {
      h = fmaf(h, dA[tt], ub[tt]);
      Pw[tt][lane] = h * Cv[tt];
    }

    // ---- batched reduction: lane L sums 16 states of timestep L>>2 ----
    float4 s0 = *(const float4*)&Pw[tt_r][c0];
    float4 s1 = *(const float4*)&Pw[tt_r][c0 + 4];
    float4 s2 = *(const float4*)&Pw[tt_r][c0 + 8];
    float4 s3 = *(const float4*)&Pw[tt_r][c0 + 12];
    float r = ((s0.x + s0.y) + (s0.z + s0.w))
            + ((s1.x + s1.y) + (s1.z + s1.w))
            + ((s2.x + s2.y) + (s2.z + s2.w))
            + ((s3.x + s3.y) + (s3.z + s3.w));
    r += __shfl_xor(r, 1, 64);
    r += __shfl_xor(r, 2, 64);
    if ((lane & 3) == 0)
      xyp[t0 + tt_r] = fmaf(xvl, dpv, r) * zs;

    // ---- stage next BC buffer, rotate prefetched registers, sync ----
    *(float4*)&BC[1 - p][0][ct][cs] = nb;
    *(float4*)&BC[1 - p][1][ct][cs] = nc;
    #pragma unroll
    for (int i = 0; i < 4; ++i) { dq[i] = nd[i]; xq[i] = nx[i]; }
    zs = nzs; xvl = nxvl;
    __syncthreads();
  }
}

// out[b,c] = h[b,L-1,:] . fc_w[c,:] + fc_b[c]; h is fp32 [4096][512]
__global__ void head_kernel(const float* __restrict__ h,
                            const float* __restrict__ fc_w,
                            const float* __restrict__ fc_b,
                            float* __restrict__ out)
{
  int bc = blockIdx.x;            // 0..11
  int b = bc / 3, c = bc % 3;
  int lane = threadIdx.x;
  const float* hr = h + (size_t)(b*1024 + 1023) * 512;
  const float* wr = fc_w + c*512;
  float s = 0.f;
  #pragma unroll
  for (int i = 0; i < 8; ++i) s = fmaf(hr[lane + i*64], wr[lane + i*64], s);
  #pragma unroll
  for (int o = 32; o > 0; o >>= 1) s += __shfl_xor(s, o, 64);
  if (lane == 0) out[b*3 + c] = s + fc_b[c];
}

extern "C" void kernel_launch(void* const* d_in, const int* in_sizes, int n_in,
                              void* d_out, int out_size, void* d_ws, size_t ws_size,
                              hipStream_t stream)
{
  const float* x        = (const float*)d_in[0];
  const float* exp_w    = (const float*)d_in[1];
  const float* exp_b    = (const float*)d_in[2];
  const float* in_w     = (const float*)d_in[3];
  const float* conv_w   = (const float*)d_in[4];
  const float* conv_b   = (const float*)d_in[5];
  const float* xproj_w  = (const float*)d_in[6];
  const float* dtproj_w = (const float*)d_in[7];
  const float* dtproj_b = (const float*)d_in[8];
  const float* A_log    = (const float*)d_in[9];
  const float* Dp       = (const float*)d_in[10];
  const float* out_w    = (const float*)d_in[11];
  const float* fc_w     = (const float*)d_in[12];
  const float* fc_b     = (const float*)d_in[13];
  float* out = (float*)d_out;

  // Workspace layout (byte offsets), 59 MB total. The 8..24 MB region is
  // sequentially reused: xcpre (in_proj -> conv_t) -> dtT (dtproj -> scan)
  // -> y16 (trans_f16 -> out_proj).
  char* ws = (char*)d_ws;
  float*    hf    = (float*)   (ws);                          //  8 MB [4096][512] fp32
  float*    xcpre = (float*)   (ws + ((size_t)8  << 20));     // 16 MB [4096][1024]
  float*    dtT   = (float*)   (ws + ((size_t)8  << 20));     // 16 MB [1024][4096] (reuse)
  _Float16* y16   = (_Float16*)(ws + ((size_t)8  << 20));     //  8 MB [4096][1024] (reuse)
  float*    xcT   = (float*)   (ws + ((size_t)24 << 20));     // 16 MB [1024][4096]
  _Float16* zsT   = (_Float16*)(ws + ((size_t)40 << 20));     //  8 MB [1024][4096]
  float*    dbc   = (float*)   (ws + ((size_t)48 << 20));     //  2.6 MB [4096][160]
  _Float16* xc16  = (_Float16*)(ws + ((size_t)51 << 20));     //  8 MB [4096][1024]

  dim3 blk(256);

  // expand: hf = x @ exp_w^T + exp_b   [4096,512] K=128, fp32 out. 512 blocks.
  gemm_mfma<0,64,0,0,0,0><<<dim3(8,64), blk, 0, stream>>>(x, 128, exp_w, exp_b,
                                                          hf, 512, 512, 128, 1.f, nullptr);

  for (int l = 0; l < 2; ++l) {
    const float* inw = in_w + (size_t)l * 2048 * 512;
    // fused in_proj: xcpre [4096][1024] f32 + zsT [1024][4096] silu f16.
    // N=2048 K=512. 1024 blocks (4/CU).
    gemm_mfma<0,128,0,0,0,1><<<dim3(16,64), blk, 0, stream>>>(hf, 512, inw, nullptr,
                                                              xcpre, 1024, 2048, 512, 1.f,
                                                              zsT);
    // conv + silu -> xcT (fp32, scan) + xc16 (f16, xproj A)
    conv_t_kernel<<<1024, blk, 0, stream>>>(xcpre, conv_w + l*2048, conv_b + l*1024,
                                            xcT, xc16);
    // xproj: dbc = xc @ xproj_w^T   [4096,160] K=1024. 192 blocks.
    gemm_mfma<1,64,0,0,0,0><<<dim3(3,64), blk, 0, stream>>>(xc16, 1024,
                                                            xproj_w + (size_t)l*160*1024,
                                                            nullptr, dbc, 160, 160, 1024,
                                                            1.f, nullptr);
    // dtproj (transposed + softplus): dtT [1024][4096], K=32. 1024 blocks.
    gemm_mfma<0,64,1,1,0,0><<<dim3(16,64), blk, 0, stream>>>(dbc, 160,
                                                             dtproj_w + (size_t)l*1024*32,
                                                             dtproj_b + l*1024,
                                                             dtT, 4096, 1024, 32, 1.f,
                                                             nullptr);
    // selective scan; y = (scan + x*Dp)*silu(z) over xcT
    scan_kernel<<<1024, blk, 0, stream>>>(dtT, xcT, zsT, dbc,
                                          A_log + (size_t)l*65536, Dp + l*1024);
    // y -> y16 = f16(y * 2^14) [4096][1024]   (overwrites dtT — dead)
    trans_f16_kernel<<<dim3(64,16), blk, 0, stream>>>(xcT, y16);
    // out_proj: hf = (y16 @ out_w^T) * 2^-14   [4096,512] K=1024. 512 blocks.
    gemm_mfma<1,64,0,0,0,0><<<dim3(8,64), blk, 0, stream>>>(y16, 1024,
                                                            out_w + (size_t)l*512*1024,
                                                            nullptr, hf, 512, 512, 1024,
                                                            1.f / Y_SCALE, nullptr);
  }

  head_kernel<<<12, 64, 0, stream>>>(hf, fc_w, fc_b, out);
}